// Round 2
// baseline (43629.086 us; speedup 1.0000x reference)
//
#include <hip/hip_runtime.h>
#include <math.h>

#define BB 2048
#define NN 15
#define DIMM 512
#define NH 8
#define GHH 4
#define DHH 64
#define MF 256
#define NLAYERS 12
#define NVOCAB 1024
#define ROWS (BB*NN)          // 30720
#define RT (ROWS/128)         // 240 row tiles

// ---------------------------------------------------------------- embed
__global__ __launch_bounds__(256) void k_embed(const int* __restrict__ xm,
                                               const float* __restrict__ emb,
                                               float* __restrict__ x1,
                                               float* __restrict__ x2) {
    int idx = blockIdx.x * 256 + threadIdx.x;       // ROWS*DIMM total
    int row = idx >> 9;
    int d   = idx & 511;
    int n   = row % NN;
    int tok = xm[row];
    int j   = d & 255;
    float invf = expf(-(float)j * (9.2103403720f / 256.f));  // 10000^(-j/256)
    float arg  = (float)n * invf;
    float pe   = (d < 256) ? sinf(arg) : cosf(arg);
    float val  = emb[tok * DIMM + d] + pe;
    x1[idx] = val;
    x2[idx] = val;
}

// ---------------------------------------------------------------- layernorm (+optional add) (+optional pre_shift)
template<int SHIFT, int ADD>
__global__ __launch_bounds__(256) void k_ln(const float* __restrict__ src,
                                            const float* __restrict__ src2,
                                            const float* __restrict__ gg,
                                            const float* __restrict__ bb,
                                            float* __restrict__ dst) {
    __shared__ float buf[NN][DIMM];
    int b    = blockIdx.x;
    int tid  = threadIdx.x;
    int wid  = tid >> 6;
    int lane = tid & 63;

    for (int n = wid; n < NN; n += 4) {
        size_t base = ((size_t)(b * NN + n)) * DIMM;
        float4 v0 = *(const float4*)(src + base + lane * 8);
        float4 v1 = *(const float4*)(src + base + lane * 8 + 4);
        if (ADD) {
            float4 w0 = *(const float4*)(src2 + base + lane * 8);
            float4 w1 = *(const float4*)(src2 + base + lane * 8 + 4);
            v0.x += w0.x; v0.y += w0.y; v0.z += w0.z; v0.w += w0.w;
            v1.x += w1.x; v1.y += w1.y; v1.z += w1.z; v1.w += w1.w;
        }
        float s = v0.x + v0.y + v0.z + v0.w + v1.x + v1.y + v1.z + v1.w;
        #pragma unroll
        for (int m = 1; m < 64; m <<= 1) s += __shfl_xor(s, m);
        float mu = s * (1.f / DIMM);
        float a0 = v0.x - mu, a1 = v0.y - mu, a2 = v0.z - mu, a3 = v0.w - mu;
        float a4 = v1.x - mu, a5 = v1.y - mu, a6 = v1.z - mu, a7 = v1.w - mu;
        float s2 = a0*a0 + a1*a1 + a2*a2 + a3*a3 + a4*a4 + a5*a5 + a6*a6 + a7*a7;
        #pragma unroll
        for (int m = 1; m < 64; m <<= 1) s2 += __shfl_xor(s2, m);
        float rstd = 1.f / sqrtf(s2 * (1.f / DIMM) + 1e-5f);
        float o[8] = {a0, a1, a2, a3, a4, a5, a6, a7};
        int d0 = lane * 8;
        #pragma unroll
        for (int i = 0; i < 8; ++i) {
            float val = o[i] * rstd * gg[d0 + i] + bb[d0 + i];
            if (SHIFT) buf[n][d0 + i] = val;
            else       dst[base + d0 + i] = val;
        }
    }
    if (SHIFT) {
        __syncthreads();
        for (int idx = tid; idx < NN * DIMM; idx += 256) {
            int n = idx >> 9, d = idx & 511;
            float val;
            if (d < 170)      val = (n < NN - 1) ? buf[n + 1][d] : 0.f;
            else if (d < 340) val = buf[n][d];
            else if (d < 510) val = (n > 0) ? buf[n - 1][d] : 0.f;
            else              val = buf[n][d];
            dst[((size_t)(b * NN + n)) * DIMM + d] = val;
        }
    }
}

// ---------------------------------------------------------------- fp32 GEMM: out = A[M,K]@W[K,N] (+bias) (+res, may alias out)
template<int BIAS, int RES>
__global__ __launch_bounds__(256) void k_sgemm(const float* __restrict__ A,
                                               const float* __restrict__ W,
                                               const float* __restrict__ bias,
                                               const float* __restrict__ res,
                                               float* __restrict__ out,
                                               int K, int Nn) {
    __shared__ __align__(16) float As[16][132];
    __shared__ __align__(16) float Bs[16][68];
    int tid  = threadIdx.x;
    int row0 = blockIdx.x * 128, col0 = blockIdx.y * 64;
    int ty = tid >> 4, tx = tid & 15;
    float acc[8][4] = {};
    for (int k0 = 0; k0 < K; k0 += 16) {
        #pragma unroll
        for (int it = 0; it < 2; ++it) {
            int f = tid + 256 * it;
            int m = f >> 2, kk = (f & 3) << 2;
            float4 v = *(const float4*)(A + (size_t)(row0 + m) * K + k0 + kk);
            As[kk][m] = v.x; As[kk + 1][m] = v.y; As[kk + 2][m] = v.z; As[kk + 3][m] = v.w;
        }
        {
            int kk = tid >> 4, c = (tid & 15) << 2;
            *(float4*)&Bs[kk][c] = *(const float4*)(W + (size_t)(k0 + kk) * Nn + col0 + c);
        }
        __syncthreads();
        #pragma unroll
        for (int kk = 0; kk < 16; ++kk) {
            float4 a0 = *(float4*)&As[kk][ty * 8];
            float4 a1 = *(float4*)&As[kk][ty * 8 + 4];
            float4 b0 = *(float4*)&Bs[kk][tx * 4];
            float av[8] = {a0.x, a0.y, a0.z, a0.w, a1.x, a1.y, a1.z, a1.w};
            float bv[4] = {b0.x, b0.y, b0.z, b0.w};
            #pragma unroll
            for (int i = 0; i < 8; ++i)
                #pragma unroll
                for (int jj = 0; jj < 4; ++jj)
                    acc[i][jj] += av[i] * bv[jj];
        }
        __syncthreads();
    }
    #pragma unroll
    for (int i = 0; i < 8; ++i) {
        int r = row0 + ty * 8 + i;
        #pragma unroll
        for (int jj = 0; jj < 4; ++jj) {
            int c = col0 + tx * 4 + jj;
            float v = acc[i][jj];
            if (BIAS) v += bias[c];
            if (RES)  v += res[(size_t)r * Nn + c];
            out[(size_t)r * Nn + c] = v;
        }
    }
}

// ---------------------------------------------------------------- GLU FF1: u = gelu(A@Wa + ba) * (A@Wg + bg); K=512, ldW=4096
__global__ __launch_bounds__(256) void k_glu_gemm(const float* __restrict__ A,
                                                  const float* __restrict__ Wa,
                                                  const float* __restrict__ Wg,
                                                  const float* __restrict__ ba,
                                                  const float* __restrict__ bg,
                                                  float* __restrict__ out, int outld) {
    __shared__ __align__(16) float As[16][132];
    __shared__ __align__(16) float Bsa[16][68];
    __shared__ __align__(16) float Bsg[16][68];
    int tid  = threadIdx.x;
    int row0 = blockIdx.x * 128, col0 = blockIdx.y * 64;
    int ty = tid >> 4, tx = tid & 15;
    float acca[8][4] = {}, accg[8][4] = {};
    for (int k0 = 0; k0 < 512; k0 += 16) {
        #pragma unroll
        for (int it = 0; it < 2; ++it) {
            int f = tid + 256 * it;
            int m = f >> 2, kk = (f & 3) << 2;
            float4 v = *(const float4*)(A + (size_t)(row0 + m) * 512 + k0 + kk);
            As[kk][m] = v.x; As[kk + 1][m] = v.y; As[kk + 2][m] = v.z; As[kk + 3][m] = v.w;
        }
        {
            int kk = tid >> 4, c = (tid & 15) << 2;
            *(float4*)&Bsa[kk][c] = *(const float4*)(Wa + (size_t)(k0 + kk) * 4096 + col0 + c);
            *(float4*)&Bsg[kk][c] = *(const float4*)(Wg + (size_t)(k0 + kk) * 4096 + col0 + c);
        }
        __syncthreads();
        #pragma unroll
        for (int kk = 0; kk < 16; ++kk) {
            float4 a0 = *(float4*)&As[kk][ty * 8];
            float4 a1 = *(float4*)&As[kk][ty * 8 + 4];
            float4 b0 = *(float4*)&Bsa[kk][tx * 4];
            float4 b1 = *(float4*)&Bsg[kk][tx * 4];
            float av[8]  = {a0.x, a0.y, a0.z, a0.w, a1.x, a1.y, a1.z, a1.w};
            float bva[4] = {b0.x, b0.y, b0.z, b0.w};
            float bvg[4] = {b1.x, b1.y, b1.z, b1.w};
            #pragma unroll
            for (int i = 0; i < 8; ++i)
                #pragma unroll
                for (int jj = 0; jj < 4; ++jj) {
                    acca[i][jj] += av[i] * bva[jj];
                    accg[i][jj] += av[i] * bvg[jj];
                }
        }
        __syncthreads();
    }
    #pragma unroll
    for (int i = 0; i < 8; ++i) {
        int r = row0 + ty * 8 + i;
        #pragma unroll
        for (int jj = 0; jj < 4; ++jj) {
            int c = col0 + tx * 4 + jj;
            float a = acca[i][jj] + ba[c];
            float g = accg[i][jj] + bg[c];
            float ge = 0.5f * a * (1.f + erff(a * 0.70710678118f));
            out[(size_t)r * outld + c] = ge * g;
        }
    }
}

// ---------------------------------------------------------------- attention: one block per (b, h); N=15 small
__global__ __launch_bounds__(256) void k_attn(const float* __restrict__ qg,
                                              const float* __restrict__ kg,
                                              const float* __restrict__ vg,
                                              const float* __restrict__ proj,
                                              float* __restrict__ out) {
    __shared__ __align__(16) float sq[NN][DHH];
    __shared__ __align__(16) float sk[NN][DHH];
    __shared__ __align__(16) float sv[NN][DHH];
    __shared__ float sqp[NN][MF + 4];
    __shared__ float skp[NN][MF + 4];
    __shared__ float sA[NN][16];
    __shared__ float sdq[NN], sdk[NN], smq[NN], sdinv[NN], sred[4];
    int b = blockIdx.x, h = blockIdx.y;
    int tid = threadIdx.x;

    for (int idx = tid; idx < NN * DHH; idx += 256) {
        int n = idx >> 6, d = idx & 63;
        size_t base = ((size_t)(b * NN + n)) * DIMM + h * DHH + d;
        sq[n][d] = qg[base]; sk[n][d] = kg[base]; sv[n][d] = vg[base];
    }
    __syncthreads();

    if (h < GHH) {
        // ---- global head: GPT-J rotary + performer features
        for (int idx = tid; idx < NN * 32; idx += 256) {
            int n = idx >> 5, i = idx & 31;
            float invf = expf(-(float)i * (9.2103403720f / 32.f));
            float cc = cosf((float)n * invf), ss = sinf((float)n * invf);
            float q0 = sq[n][2*i], q1 = sq[n][2*i + 1];
            sq[n][2*i] = q0 * cc - q1 * ss; sq[n][2*i + 1] = q1 * cc + q0 * ss;
            float k0 = sk[n][2*i], k1 = sk[n][2*i + 1];
            sk[n][2*i] = k0 * cc - k1 * ss; sk[n][2*i + 1] = k1 * cc + k0 * ss;
        }
        __syncthreads();
        // diag = 0.5*dn^2*||x||^2 per row (16 lanes per row)
        {
            int r = tid >> 4, l = tid & 15;
            if (r < NN) {
                float sa = 0.f, sb = 0.f;
                #pragma unroll
                for (int j = 0; j < 4; ++j) {
                    float x = sq[r][l + 16 * j]; sa += x * x;
                    float y = sk[r][l + 16 * j]; sb += y * y;
                }
                #pragma unroll
                for (int m = 1; m < 16; m <<= 1) { sa += __shfl_xor(sa, m); sb += __shfl_xor(sb, m); }
                if (l == 0) { sdq[r] = 0.0625f * sa; sdk[r] = 0.0625f * sb; }
            }
        }
        __syncthreads();
        // dash = dn * (x @ proj^T): thread = feature m
        float dq[NN], dk[NN];
        #pragma unroll
        for (int n = 0; n < NN; ++n) { dq[n] = 0.f; dk[n] = 0.f; }
        const float* pr = proj + (size_t)tid * DHH;
        #pragma unroll 4
        for (int d4 = 0; d4 < 16; ++d4) {
            float4 p = *(const float4*)(pr + d4 * 4);
            #pragma unroll
            for (int n = 0; n < NN; ++n) {
                float4 aq = *(float4*)&sq[n][d4 * 4];
                float4 ak = *(float4*)&sk[n][d4 * 4];
                dq[n] += p.x * aq.x + p.y * aq.y + p.z * aq.z + p.w * aq.w;
                dk[n] += p.x * ak.x + p.y * ak.y + p.z * ak.z + p.w * ak.w;
            }
        }
        const float dn = 0.35355339059f;   // 64^-0.25
        float mk = -1e30f;
        #pragma unroll
        for (int n = 0; n < NN; ++n) { dq[n] *= dn; dk[n] *= dn; mk = fmaxf(mk, dk[n]); }
        #pragma unroll
        for (int m = 1; m < 64; m <<= 1) mk = fmaxf(mk, __shfl_xor(mk, m));
        if ((tid & 63) == 0) sred[tid >> 6] = mk;
        __syncthreads();
        mk = fmaxf(fmaxf(sred[0], sred[1]), fmaxf(sred[2], sred[3]));
        #pragma unroll
        for (int n = 0; n < NN; ++n) {
            sqp[n][tid] = dq[n];  // raw dash_q for row-max
            skp[n][tid] = 0.0625f * (expf(dk[n] - sdk[n] - mk) + 1e-4f);
        }
        __syncthreads();
        {
            int r = tid >> 4, l = tid & 15;
            if (r < NN) {
                float mx = -1e30f;
                #pragma unroll
                for (int j = 0; j < 16; ++j) mx = fmaxf(mx, sqp[r][l + 16 * j]);
                #pragma unroll
                for (int m = 1; m < 16; m <<= 1) mx = fmaxf(mx, __shfl_xor(mx, m));
                if (l == 0) smq[r] = mx;
            }
        }
        __syncthreads();
        #pragma unroll
        for (int n = 0; n < NN; ++n)
            sqp[n][tid] = 0.0625f * (expf(dq[n] - sdq[n] - smq[n]) + 1e-4f);
        __syncthreads();
        // scores A = qp @ kp^T  (15x15); d_inv = 1/rowsum(A)
        if (tid < NN * NN) {
            int i = tid / NN, j = tid % NN;
            float s = 0.f;
            for (int m = 0; m < MF; ++m) s += sqp[i][m] * skp[j][m];
            sA[i][j] = s;
        }
    } else {
        // ---- local head: NeoX rotary + softmax attention
        for (int idx = tid; idx < NN * 32; idx += 256) {
            int n = idx >> 5, i = idx & 31;
            float invf = expf(-(float)i * (9.2103403720f / 32.f));
            float cc = cosf((float)n * invf), ss = sinf((float)n * invf);
            float qlo = sq[n][i], qhi = sq[n][i + 32];
            sq[n][i] = qlo * cc - qhi * ss; sq[n][i + 32] = qhi * cc + qlo * ss;
            float klo = sk[n][i], khi = sk[n][i + 32];
            sk[n][i] = klo * cc - khi * ss; sk[n][i + 32] = khi * cc + klo * ss;
        }
        __syncthreads();
        if (tid < NN * NN) {
            int i = tid / NN, j = tid % NN;
            float s = 0.f;
            #pragma unroll
            for (int d = 0; d < DHH; ++d) s += sq[i][d] * sk[j][d];
            sA[i][j] = s * 0.125f;   // 64^-0.5
        }
    }
    __syncthreads();
    if (tid < NN) {
        if (h < GHH) {
            float s = 0.f;
            #pragma unroll
            for (int j = 0; j < NN; ++j) s += sA[tid][j];
            sdinv[tid] = 1.f / s;
        } else {
            float mx = -1e30f;
            #pragma unroll
            for (int j = 0; j < NN; ++j) mx = fmaxf(mx, sA[tid][j]);
            float s = 0.f;
            #pragma unroll
            for (int j = 0; j < NN; ++j) { float e = expf(sA[tid][j] - mx); sA[tid][j] = e; s += e; }
            sdinv[tid] = 1.f / s;
        }
    }
    __syncthreads();
    for (int idx = tid; idx < NN * DHH; idx += 256) {
        int n = idx >> 6, e = idx & 63;
        float o = 0.f;
        #pragma unroll
        for (int j = 0; j < NN; ++j) o += sA[n][j] * sv[j][e];
        out[((size_t)(b * NN + n)) * DIMM + h * DHH + e] = o * sdinv[n];
    }
}

// ---------------------------------------------------------------- final head: mean over n, 2-layer MLP
__global__ __launch_bounds__(256) void k_head(const float* __restrict__ logits,
                                              const float* __restrict__ Wl1,
                                              const float* __restrict__ bl1,
                                              const float* __restrict__ Wl2,
                                              const float* __restrict__ bl2,
                                              float* __restrict__ outp) {
    __shared__ float xa[NVOCAB];
    __shared__ float hh[64];
    int b = blockIdx.x, tid = threadIdx.x;
    for (int c = tid; c < NVOCAB; c += 256) {
        float s = 0.f;
        #pragma unroll
        for (int n = 0; n < NN; ++n) s += logits[((size_t)(b * NN + n)) * NVOCAB + c];
        xa[c] = s * (1.f / NN);
    }
    __syncthreads();
    if (tid < 64) {
        float s = bl1[tid];
        for (int kk = 0; kk < NVOCAB; ++kk) s += xa[kk] * Wl1[kk * 64 + tid];
        hh[tid] = fmaxf(s, 0.f);
    }
    __syncthreads();
    if (tid < 2) {
        float s = bl2[tid];
        #pragma unroll
        for (int j = 0; j < 64; ++j) s += hh[j] * Wl2[j * 2 + tid];
        outp[(size_t)b * 2 + tid] = s;
    }
}

// ---------------------------------------------------------------- host
extern "C" void kernel_launch(void* const* d_in, const int* in_sizes, int n_in,
                              void* d_out, int out_size, void* d_ws, size_t ws_size,
                              hipStream_t stream) {
    (void)in_sizes; (void)n_in; (void)out_size; (void)ws_size;
    const int*   x_mcc = (const int*)d_in[0];
    const float* emb   = (const float*)d_in[1];
    const float* ln1g  = (const float*)d_in[2];
    const float* ln1b  = (const float*)d_in[3];
    const float* Wq    = (const float*)d_in[4];
    const float* Wk    = (const float*)d_in[5];
    const float* Wv    = (const float*)d_in[6];
    const float* Wo    = (const float*)d_in[7];
    const float* bo    = (const float*)d_in[8];
    const float* proj  = (const float*)d_in[9];
    const float* ln2g  = (const float*)d_in[10];
    const float* ln2b  = (const float*)d_in[11];
    const float* W1    = (const float*)d_in[12];
    const float* b1    = (const float*)d_in[13];
    const float* W2    = (const float*)d_in[14];
    const float* b2    = (const float*)d_in[15];
    const float* lnfg  = (const float*)d_in[16];
    const float* lnfb  = (const float*)d_in[17];
    const float* Wout  = (const float*)d_in[18];
    const float* bout  = (const float*)d_in[19];
    const float* Wl1   = (const float*)d_in[20];
    const float* bl1   = (const float*)d_in[21];
    const float* Wl2   = (const float*)d_in[22];
    const float* bl2   = (const float*)d_in[23];
    float* outp = (float*)d_out;

    // Workspace layout: 6 buffers of S = ROWS*512*4 = 62.9 MB -> 377 MB total.
    //   x1, x2   : residual streams
    //   xs       : ln/pre_shift output, then attn output
    //   qb,kb,vb : QKV; after attn dead -> ub (GLU hidden chunk) = qb,
    //              logits (2S) = qb..kb (contiguous)
    char* ws = (char*)d_ws;
    const size_t S = (size_t)ROWS * DIMM * sizeof(float);
    float* x1 = (float*)(ws);
    float* x2 = (float*)(ws + 1 * S);
    float* xs = (float*)(ws + 2 * S);
    float* qb = (float*)(ws + 3 * S);
    float* kb = (float*)(ws + 4 * S);
    float* vb = (float*)(ws + 5 * S);
    float* ub = qb;          // GLU hidden chunk (512 cols = 1S), qkv dead by then
    float* logits = qb;      // ROWS x 1024 = 2S spans qb+kb, dead by then
    const int CH = 4;        // 2048 / 4 = 512 hidden cols per chunk
    const int ucols = 2048 / CH;

    k_embed<<<(ROWS * DIMM) / 256, 256, 0, stream>>>(x_mcc, emb, x1, x2);

    for (int l = 0; l < NLAYERS; ++l) {
        const size_t wo512 = (size_t)l * DIMM * DIMM;
        k_ln<1, 0><<<BB, 256, 0, stream>>>(x2, nullptr, ln1g + l * DIMM, ln1b + l * DIMM, xs);
        k_sgemm<0, 0><<<dim3(RT, 8), 256, 0, stream>>>(xs, Wq + wo512, nullptr, nullptr, qb, 512, 512);
        k_sgemm<0, 0><<<dim3(RT, 8), 256, 0, stream>>>(xs, Wk + wo512, nullptr, nullptr, kb, 512, 512);
        k_sgemm<0, 0><<<dim3(RT, 8), 256, 0, stream>>>(xs, Wv + wo512, nullptr, nullptr, vb, 512, 512);
        k_attn<<<dim3(BB, NH), 256, 0, stream>>>(qb, kb, vb, proj + (size_t)l * MF * DHH, xs);
        k_sgemm<1, 1><<<dim3(RT, 8), 256, 0, stream>>>(xs, Wo + wo512, bo + l * DIMM, x1, x1, 512, 512);
        k_ln<1, 0><<<BB, 256, 0, stream>>>(x1, nullptr, ln2g + l * DIMM, ln2b + l * DIMM, xs);
        for (int ch = 0; ch < CH; ++ch) {
            int cbase = ch * ucols;
            k_glu_gemm<<<dim3(RT, ucols / 64), 256, 0, stream>>>(
                xs,
                W1 + (size_t)l * DIMM * 4096 + cbase,
                W1 + (size_t)l * DIMM * 4096 + 2048 + cbase,
                b1 + (size_t)l * 4096 + cbase,
                b1 + (size_t)l * 4096 + 2048 + cbase,
                ub, ucols);
            if (ch == 0)
                k_sgemm<1, 1><<<dim3(RT, 8), 256, 0, stream>>>(ub, W2 + (size_t)l * 2048 * DIMM + (size_t)cbase * DIMM,
                                                               b2 + l * DIMM, x2, x2, ucols, 512);
            else
                k_sgemm<0, 1><<<dim3(RT, 8), 256, 0, stream>>>(ub, W2 + (size_t)l * 2048 * DIMM + (size_t)cbase * DIMM,
                                                               nullptr, x2, x2, ucols, 512);
        }
    }

    k_ln<0, 1><<<BB, 256, 0, stream>>>(x1, x2, lnfg, lnfb, xs);
    k_sgemm<1, 0><<<dim3(RT, 16), 256, 0, stream>>>(xs, Wout, bout, nullptr, logits, 512, 1024);
    k_head<<<BB, 256, 0, stream>>>(logits, Wl1, bl1, Wl2, bl2, outp);
}

// Round 3
// 12592.098 us; speedup vs baseline: 3.4648x; 3.4648x over previous
//
#include <hip/hip_runtime.h>
#include <math.h>

#define BB 2048
#define NN 15
#define DIMM 512
#define NH 8
#define GHH 4
#define DHH 64
#define MF 256
#define NLAYERS 12
#define NVOCAB 1024
#define ROWS (BB*NN)          // 30720
#define RT (ROWS/128)         // 240 row tiles

typedef __attribute__((ext_vector_type(8))) short s8b;
typedef __attribute__((ext_vector_type(4))) float f4;
typedef unsigned short ushort;
typedef unsigned int uint;

__device__ __forceinline__ ushort f2b(float f) {
    uint u = __builtin_bit_cast(uint, f);
    u = u + 0x7FFF + ((u >> 16) & 1);
    return (ushort)(u >> 16);
}
__device__ __forceinline__ float b2f(ushort b) {
    return __builtin_bit_cast(float, (uint)b << 16);
}
__device__ __forceinline__ void gll16(const ushort* g, ushort* l) {
    __builtin_amdgcn_global_load_lds(
        (const __attribute__((address_space(1))) uint*)g,
        (__attribute__((address_space(3))) uint*)l, 16, 0, 0);
}

// ---------------------------------------------------------------- embed
__global__ __launch_bounds__(256) void k_embed(const int* __restrict__ xm,
                                               const float* __restrict__ emb,
                                               float* __restrict__ x1,
                                               float* __restrict__ x2) {
    int idx = blockIdx.x * 256 + threadIdx.x;
    int row = idx >> 9;
    int d   = idx & 511;
    int n   = row % NN;
    int tok = xm[row];
    int j   = d & 255;
    float invf = expf(-(float)j * (9.2103403720f / 256.f));
    float arg  = (float)n * invf;
    float pe   = (d < 256) ? sinf(arg) : cosf(arg);
    float val  = emb[tok * DIMM + d] + pe;
    x1[idx] = val;
    x2[idx] = val;
}

// ---------------------------------------------------------------- layernorm (+optional add)(+pre_shift), bf16 out
template<int SHIFT, int ADD>
__global__ __launch_bounds__(256) void k_ln(const float* __restrict__ src,
                                            const float* __restrict__ src2,
                                            const float* __restrict__ gg,
                                            const float* __restrict__ bb,
                                            ushort* __restrict__ dst) {
    __shared__ float buf[NN][DIMM];
    int b    = blockIdx.x;
    int tid  = threadIdx.x;
    int wid  = tid >> 6;
    int lane = tid & 63;

    for (int n = wid; n < NN; n += 4) {
        size_t base = ((size_t)(b * NN + n)) * DIMM;
        float4 v0 = *(const float4*)(src + base + lane * 8);
        float4 v1 = *(const float4*)(src + base + lane * 8 + 4);
        if (ADD) {
            float4 w0 = *(const float4*)(src2 + base + lane * 8);
            float4 w1 = *(const float4*)(src2 + base + lane * 8 + 4);
            v0.x += w0.x; v0.y += w0.y; v0.z += w0.z; v0.w += w0.w;
            v1.x += w1.x; v1.y += w1.y; v1.z += w1.z; v1.w += w1.w;
        }
        float s = v0.x + v0.y + v0.z + v0.w + v1.x + v1.y + v1.z + v1.w;
        #pragma unroll
        for (int m = 1; m < 64; m <<= 1) s += __shfl_xor(s, m);
        float mu = s * (1.f / DIMM);
        float a0 = v0.x - mu, a1 = v0.y - mu, a2 = v0.z - mu, a3 = v0.w - mu;
        float a4 = v1.x - mu, a5 = v1.y - mu, a6 = v1.z - mu, a7 = v1.w - mu;
        float s2 = a0*a0 + a1*a1 + a2*a2 + a3*a3 + a4*a4 + a5*a5 + a6*a6 + a7*a7;
        #pragma unroll
        for (int m = 1; m < 64; m <<= 1) s2 += __shfl_xor(s2, m);
        float rstd = 1.f / sqrtf(s2 * (1.f / DIMM) + 1e-5f);
        float o[8] = {a0, a1, a2, a3, a4, a5, a6, a7};
        int d0 = lane * 8;
        #pragma unroll
        for (int i = 0; i < 8; ++i) {
            float val = o[i] * rstd * gg[d0 + i] + bb[d0 + i];
            if (SHIFT) buf[n][d0 + i] = val;
            else       dst[base + d0 + i] = f2b(val);
        }
    }
    if (SHIFT) {
        __syncthreads();
        for (int idx = tid; idx < NN * DIMM; idx += 256) {
            int n = idx >> 9, d = idx & 511;
            float val;
            if (d < 170)      val = (n < NN - 1) ? buf[n + 1][d] : 0.f;
            else if (d < 340) val = buf[n][d];
            else if (d < 510) val = (n > 0) ? buf[n - 1][d] : 0.f;
            else              val = buf[n][d];
            dst[((size_t)(b * NN + n)) * DIMM + d] = f2b(val);
        }
    }
}

// ---------------------------------------------------------------- weight transpose fp32[K][N] -> bf16[N][K]
__global__ __launch_bounds__(256) void k_wt(const float* __restrict__ src,
                                            ushort* __restrict__ dst, int K, int N) {
    __shared__ float t[32][33];
    int n0 = blockIdx.x * 32, k0 = blockIdx.y * 32;
    int tx = threadIdx.x & 31, ty = threadIdx.x >> 5;
    #pragma unroll
    for (int i = 0; i < 32; i += 8)
        t[ty + i][tx] = src[(size_t)(k0 + ty + i) * N + n0 + tx];
    __syncthreads();
    #pragma unroll
    for (int i = 0; i < 32; i += 8)
        dst[(size_t)(n0 + ty + i) * K + k0 + tx] = f2b(t[tx][ty + i]);
}

// ---------------------------------------------------------------- bf16 MFMA GEMM: out = A[M,K](bf16) @ Bt[N,K](bf16)^T
// m97 structure: 128x128 tile, BK=32, 4 waves (2x2), 4x4 frags of 16x16x32
template<int OUTB, int BIAS, int RES>
__global__ __launch_bounds__(256) void k_mm(const ushort* __restrict__ A,
                                            const ushort* __restrict__ Bt,
                                            const float* __restrict__ bias,
                                            const float* __restrict__ res,
                                            void* __restrict__ outv,
                                            int lda, int ldb, int K, int ldo) {
    __shared__ ushort smA[128 * 32];
    __shared__ ushort smB[128 * 32];
    int tid = threadIdx.x, wid = tid >> 6, lane = tid & 63;
    int row0 = blockIdx.x * 128, col0 = blockIdx.y * 128;
    int trow = tid >> 2, tkk = (tid & 3) * 8;
    f4 acc[4][4] = {};
    int rw = (wid >> 1) * 64, cw = (wid & 1) * 64;

    for (int k0 = 0; k0 < K; k0 += 32) {
        #pragma unroll
        for (int r = 0; r < 2; ++r) {
            gll16(A  + (size_t)(row0 + r * 64 + trow) * lda + k0 + tkk, smA + (r * 256 + wid * 64) * 8);
            gll16(Bt + (size_t)(col0 + r * 64 + trow) * ldb + k0 + tkk, smB + (r * 256 + wid * 64) * 8);
        }
        __syncthreads();
        s8b af[4], bf[4];
        #pragma unroll
        for (int m = 0; m < 4; ++m)
            af[m] = *(const s8b*)(smA + (rw + m * 16 + (lane & 15)) * 32 + (lane >> 4) * 8);
        #pragma unroll
        for (int n = 0; n < 4; ++n)
            bf[n] = *(const s8b*)(smB + (cw + n * 16 + (lane & 15)) * 32 + (lane >> 4) * 8);
        #pragma unroll
        for (int m = 0; m < 4; ++m)
            #pragma unroll
            for (int n = 0; n < 4; ++n)
                acc[m][n] = __builtin_amdgcn_mfma_f32_16x16x32_bf16(af[m], bf[n], acc[m][n], 0, 0, 0);
        __syncthreads();
    }
    #pragma unroll
    for (int m = 0; m < 4; ++m) {
        #pragma unroll
        for (int n = 0; n < 4; ++n) {
            int c = col0 + cw + n * 16 + (lane & 15);
            #pragma unroll
            for (int j = 0; j < 4; ++j) {
                int r = row0 + rw + m * 16 + (lane >> 4) * 4 + j;
                float v = acc[m][n][j];
                if (BIAS) v += bias[c];
                if (RES)  v += res[(size_t)r * ldo + c];
                if (OUTB) ((ushort*)outv)[(size_t)r * ldo + c] = f2b(v);
                else      ((float*)outv)[(size_t)r * ldo + c] = v;
            }
        }
    }
}

// ---------------------------------------------------------------- GLU FF1 MFMA: out = gelu(A@Wa+ba)*(A@Wg+bg), bf16 out
__global__ __launch_bounds__(256) void k_glu(const ushort* __restrict__ A,
                                             const ushort* __restrict__ Ba,
                                             const ushort* __restrict__ Bg,
                                             const float* __restrict__ ba,
                                             const float* __restrict__ bg,
                                             ushort* __restrict__ outp) {
    __shared__ ushort smA[128 * 32];
    __shared__ ushort smBa[128 * 32];
    __shared__ ushort smBg[128 * 32];
    int tid = threadIdx.x, wid = tid >> 6, lane = tid & 63;
    int row0 = blockIdx.x * 128, col0 = blockIdx.y * 128;
    int trow = tid >> 2, tkk = (tid & 3) * 8;
    f4 acca[4][4] = {}, accg[4][4] = {};
    int rw = (wid >> 1) * 64, cw = (wid & 1) * 64;

    for (int k0 = 0; k0 < 512; k0 += 32) {
        #pragma unroll
        for (int r = 0; r < 2; ++r) {
            gll16(A  + (size_t)(row0 + r * 64 + trow) * 512 + k0 + tkk, smA  + (r * 256 + wid * 64) * 8);
            gll16(Ba + (size_t)(col0 + r * 64 + trow) * 512 + k0 + tkk, smBa + (r * 256 + wid * 64) * 8);
            gll16(Bg + (size_t)(col0 + r * 64 + trow) * 512 + k0 + tkk, smBg + (r * 256 + wid * 64) * 8);
        }
        __syncthreads();
        s8b af[4], bfa[4], bfg[4];
        #pragma unroll
        for (int m = 0; m < 4; ++m)
            af[m] = *(const s8b*)(smA + (rw + m * 16 + (lane & 15)) * 32 + (lane >> 4) * 8);
        #pragma unroll
        for (int n = 0; n < 4; ++n) {
            bfa[n] = *(const s8b*)(smBa + (cw + n * 16 + (lane & 15)) * 32 + (lane >> 4) * 8);
            bfg[n] = *(const s8b*)(smBg + (cw + n * 16 + (lane & 15)) * 32 + (lane >> 4) * 8);
        }
        #pragma unroll
        for (int m = 0; m < 4; ++m)
            #pragma unroll
            for (int n = 0; n < 4; ++n) {
                acca[m][n] = __builtin_amdgcn_mfma_f32_16x16x32_bf16(af[m], bfa[n], acca[m][n], 0, 0, 0);
                accg[m][n] = __builtin_amdgcn_mfma_f32_16x16x32_bf16(af[m], bfg[n], accg[m][n], 0, 0, 0);
            }
        __syncthreads();
    }
    #pragma unroll
    for (int m = 0; m < 4; ++m) {
        #pragma unroll
        for (int n = 0; n < 4; ++n) {
            int c = col0 + cw + n * 16 + (lane & 15);
            float biasa = ba[c], biasg = bg[c];
            #pragma unroll
            for (int j = 0; j < 4; ++j) {
                int r = row0 + rw + m * 16 + (lane >> 4) * 4 + j;
                float a = acca[m][n][j] + biasa;
                float g = accg[m][n][j] + biasg;
                float ge = 0.5f * a * (1.f + erff(a * 0.70710678118f));
                outp[(size_t)r * 1024 + c] = f2b(ge * g);
            }
        }
    }
}

// ---------------------------------------------------------------- global-head attention (performer), bf16 in/out
__global__ __launch_bounds__(256) void k_attng(const ushort* __restrict__ qkv,
                                               const float* __restrict__ proj,
                                               ushort* __restrict__ outp) {
    __shared__ __align__(16) float sq[NN][DHH];
    __shared__ __align__(16) float sk[NN][DHH];
    __shared__ __align__(16) float sv[NN][DHH];
    __shared__ float sqp[NN][MF + 4];
    __shared__ float skp[NN][MF + 4];
    __shared__ float sA[NN][16];
    __shared__ float sdq[NN], sdk[NN], smq[NN], sdinv[NN], sred[4];
    int b = blockIdx.x, h = blockIdx.y;
    int tid = threadIdx.x;

    for (int idx = tid; idx < NN * DHH; idx += 256) {
        int n = idx >> 6, d = idx & 63;
        size_t base = ((size_t)(b * NN + n)) * 1536 + h * DHH + d;
        sq[n][d] = b2f(qkv[base]);
        sk[n][d] = b2f(qkv[base + 512]);
        sv[n][d] = b2f(qkv[base + 1024]);
    }
    __syncthreads();

    // GPT-J rotary
    for (int idx = tid; idx < NN * 32; idx += 256) {
        int n = idx >> 5, i = idx & 31;
        float invf = expf(-(float)i * (9.2103403720f / 32.f));
        float cc = cosf((float)n * invf), ss = sinf((float)n * invf);
        float q0 = sq[n][2*i], q1 = sq[n][2*i + 1];
        sq[n][2*i] = q0 * cc - q1 * ss; sq[n][2*i + 1] = q1 * cc + q0 * ss;
        float k0 = sk[n][2*i], k1 = sk[n][2*i + 1];
        sk[n][2*i] = k0 * cc - k1 * ss; sk[n][2*i + 1] = k1 * cc + k0 * ss;
    }
    __syncthreads();
    {
        int r = tid >> 4, l = tid & 15;
        if (r < NN) {
            float sa = 0.f, sb = 0.f;
            #pragma unroll
            for (int j = 0; j < 4; ++j) {
                float x = sq[r][l + 16 * j]; sa += x * x;
                float y = sk[r][l + 16 * j]; sb += y * y;
            }
            #pragma unroll
            for (int m = 1; m < 16; m <<= 1) { sa += __shfl_xor(sa, m); sb += __shfl_xor(sb, m); }
            if (l == 0) { sdq[r] = 0.0625f * sa; sdk[r] = 0.0625f * sb; }
        }
    }
    __syncthreads();
    float dq[NN], dk[NN];
    #pragma unroll
    for (int n = 0; n < NN; ++n) { dq[n] = 0.f; dk[n] = 0.f; }
    const float* pr = proj + (size_t)tid * DHH;
    #pragma unroll 4
    for (int d4 = 0; d4 < 16; ++d4) {
        float4 p = *(const float4*)(pr + d4 * 4);
        #pragma unroll
        for (int n = 0; n < NN; ++n) {
            float4 aq = *(float4*)&sq[n][d4 * 4];
            float4 ak = *(float4*)&sk[n][d4 * 4];
            dq[n] += p.x * aq.x + p.y * aq.y + p.z * aq.z + p.w * aq.w;
            dk[n] += p.x * ak.x + p.y * ak.y + p.z * ak.z + p.w * ak.w;
        }
    }
    const float dn = 0.35355339059f;   // 64^-0.25
    float mk = -1e30f;
    #pragma unroll
    for (int n = 0; n < NN; ++n) { dq[n] *= dn; dk[n] *= dn; mk = fmaxf(mk, dk[n]); }
    #pragma unroll
    for (int m = 1; m < 64; m <<= 1) mk = fmaxf(mk, __shfl_xor(mk, m));
    if ((tid & 63) == 0) sred[tid >> 6] = mk;
    __syncthreads();
    mk = fmaxf(fmaxf(sred[0], sred[1]), fmaxf(sred[2], sred[3]));
    #pragma unroll
    for (int n = 0; n < NN; ++n) {
        sqp[n][tid] = dq[n];
        skp[n][tid] = 0.0625f * (expf(dk[n] - sdk[n] - mk) + 1e-4f);
    }
    __syncthreads();
    {
        int r = tid >> 4, l = tid & 15;
        if (r < NN) {
            float mx = -1e30f;
            #pragma unroll
            for (int j = 0; j < 16; ++j) mx = fmaxf(mx, sqp[r][l + 16 * j]);
            #pragma unroll
            for (int m = 1; m < 16; m <<= 1) mx = fmaxf(mx, __shfl_xor(mx, m));
            if (l == 0) smq[r] = mx;
        }
    }
    __syncthreads();
    #pragma unroll
    for (int n = 0; n < NN; ++n)
        sqp[n][tid] = 0.0625f * (expf(dq[n] - sdq[n] - smq[n]) + 1e-4f);
    __syncthreads();
    if (tid < NN * NN) {
        int i = tid / NN, j = tid % NN;
        float s = 0.f;
        for (int m = 0; m < MF; ++m) s += sqp[i][m] * skp[j][m];
        sA[i][j] = s;
    }
    __syncthreads();
    if (tid < NN) {
        float s = 0.f;
        #pragma unroll
        for (int j = 0; j < NN; ++j) s += sA[tid][j];
        sdinv[tid] = 1.f / s;
    }
    __syncthreads();
    for (int idx = tid; idx < NN * DHH; idx += 256) {
        int n = idx >> 6, e = idx & 63;
        float o = 0.f;
        #pragma unroll
        for (int j = 0; j < NN; ++j) o += sA[n][j] * sv[j][e];
        outp[((size_t)(b * NN + n)) * DIMM + h * DHH + e] = f2b(o * sdinv[n]);
    }
}

// ---------------------------------------------------------------- local-head attention (softmax), bf16 in/out
__global__ __launch_bounds__(256) void k_attnl(const ushort* __restrict__ qkv,
                                               ushort* __restrict__ outp) {
    __shared__ __align__(16) float sq[NN][DHH];
    __shared__ __align__(16) float sk[NN][DHH];
    __shared__ __align__(16) float sv[NN][DHH];
    __shared__ float sA[NN][16];
    __shared__ float sdinv[NN];
    int b = blockIdx.x, h = blockIdx.y + GHH;
    int tid = threadIdx.x;

    for (int idx = tid; idx < NN * DHH; idx += 256) {
        int n = idx >> 6, d = idx & 63;
        size_t base = ((size_t)(b * NN + n)) * 1536 + h * DHH + d;
        sq[n][d] = b2f(qkv[base]);
        sk[n][d] = b2f(qkv[base + 512]);
        sv[n][d] = b2f(qkv[base + 1024]);
    }
    __syncthreads();
    // NeoX rotary
    for (int idx = tid; idx < NN * 32; idx += 256) {
        int n = idx >> 5, i = idx & 31;
        float invf = expf(-(float)i * (9.2103403720f / 32.f));
        float cc = cosf((float)n * invf), ss = sinf((float)n * invf);
        float qlo = sq[n][i], qhi = sq[n][i + 32];
        sq[n][i] = qlo * cc - qhi * ss; sq[n][i + 32] = qhi * cc + qlo * ss;
        float klo = sk[n][i], khi = sk[n][i + 32];
        sk[n][i] = klo * cc - khi * ss; sk[n][i + 32] = khi * cc + klo * ss;
    }
    __syncthreads();
    if (tid < NN * NN) {
        int i = tid / NN, j = tid % NN;
        float s = 0.f;
        #pragma unroll
        for (int d = 0; d < DHH; ++d) s += sq[i][d] * sk[j][d];
        sA[i][j] = s * 0.125f;
    }
    __syncthreads();
    if (tid < NN) {
        float mx = -1e30f;
        #pragma unroll
        for (int j = 0; j < NN; ++j) mx = fmaxf(mx, sA[tid][j]);
        float s = 0.f;
        #pragma unroll
        for (int j = 0; j < NN; ++j) { float e = expf(sA[tid][j] - mx); sA[tid][j] = e; s += e; }
        sdinv[tid] = 1.f / s;
    }
    __syncthreads();
    for (int idx = tid; idx < NN * DHH; idx += 256) {
        int n = idx >> 6, e = idx & 63;
        float o = 0.f;
        #pragma unroll
        for (int j = 0; j < NN; ++j) o += sA[n][j] * sv[j][e];
        outp[((size_t)(b * NN + n)) * DIMM + h * DHH + e] = f2b(o * sdinv[n]);
    }
}

// ---------------------------------------------------------------- final head
__global__ __launch_bounds__(256) void k_head(const float* __restrict__ logits,
                                              const float* __restrict__ Wl1,
                                              const float* __restrict__ bl1,
                                              const float* __restrict__ Wl2,
                                              const float* __restrict__ bl2,
                                              float* __restrict__ outp) {
    __shared__ float xa[NVOCAB];
    __shared__ float hh[64];
    int b = blockIdx.x, tid = threadIdx.x;
    for (int c = tid; c < NVOCAB; c += 256) {
        float s = 0.f;
        #pragma unroll
        for (int n = 0; n < NN; ++n) s += logits[((size_t)(b * NN + n)) * NVOCAB + c];
        xa[c] = s * (1.f / NN);
    }
    __syncthreads();
    if (tid < 64) {
        float s = bl1[tid];
        for (int kk = 0; kk < NVOCAB; ++kk) s += xa[kk] * Wl1[kk * 64 + tid];
        hh[tid] = fmaxf(s, 0.f);
    }
    __syncthreads();
    if (tid < 2) {
        float s = bl2[tid];
        #pragma unroll
        for (int j = 0; j < 64; ++j) s += hh[j] * Wl2[j * 2 + tid];
        outp[(size_t)b * 2 + tid] = s;
    }
}

// ---------------------------------------------------------------- host
extern "C" void kernel_launch(void* const* d_in, const int* in_sizes, int n_in,
                              void* d_out, int out_size, void* d_ws, size_t ws_size,
                              hipStream_t stream) {
    (void)in_sizes; (void)n_in; (void)out_size; (void)ws_size;
    const int*   x_mcc = (const int*)d_in[0];
    const float* emb   = (const float*)d_in[1];
    const float* ln1g  = (const float*)d_in[2];
    const float* ln1b  = (const float*)d_in[3];
    const float* Wq    = (const float*)d_in[4];
    const float* Wk    = (const float*)d_in[5];
    const float* Wv    = (const float*)d_in[6];
    const float* Wo    = (const float*)d_in[7];
    const float* bo    = (const float*)d_in[8];
    const float* proj  = (const float*)d_in[9];
    const float* ln2g  = (const float*)d_in[10];
    const float* ln2b  = (const float*)d_in[11];
    const float* W1    = (const float*)d_in[12];
    const float* b1    = (const float*)d_in[13];
    const float* W2    = (const float*)d_in[14];
    const float* b2    = (const float*)d_in[15];
    const float* lnfg  = (const float*)d_in[16];
    const float* lnfb  = (const float*)d_in[17];
    const float* Wout  = (const float*)d_in[18];
    const float* bout  = (const float*)d_in[19];
    const float* Wl1   = (const float*)d_in[20];
    const float* bl1   = (const float*)d_in[21];
    const float* Wl2   = (const float*)d_in[22];
    const float* bl2   = (const float*)d_in[23];
    float* outp = (float*)d_out;

    // ws layout (S = ROWS*512*4 = 62.9MB): x1(S) x2(S) xs(S/2,bf16) qkv(1.5S,bf16)
    //   ub(S,bf16 [30720][1024]) wbuf(8MB). logits fp32 2S aliases qkv+ub region.
    char* ws = (char*)d_ws;
    const size_t S = (size_t)ROWS * DIMM * 4;
    float*  x1   = (float*)(ws);
    float*  x2   = (float*)(ws + S);
    ushort* xs   = (ushort*)(ws + 2 * S);
    ushort* qkv  = (ushort*)(ws + 2 * S + S / 2);
    ushort* ub   = (ushort*)(ws + 4 * S);
    ushort* wb   = (ushort*)(ws + 5 * S);
    float*  logits = (float*)(ws + 2 * S + S / 2);   // 2S, qkv+ub dead by then
    ushort* qkvT = wb;                               // [1536][512]
    ushort* woT  = wb + 1536 * 512;                  // [512][512]
    ushort* w1T  = wb + 1536 * 512 + 512 * 512;      // [4096][512]
    ushort* w2T  = w1T + 4096 * 512;                 // [512][2048]
    ushort* woutT = w1T;                             // [1024][512], reused at end

    k_embed<<<(ROWS * DIMM) / 256, 256, 0, stream>>>(x_mcc, emb, x1, x2);

    for (int l = 0; l < NLAYERS; ++l) {
        const size_t w512 = (size_t)l * 512 * 512;
        k_wt<<<dim3(16, 16), 256, 0, stream>>>(Wq + w512, qkvT,             512, 512);
        k_wt<<<dim3(16, 16), 256, 0, stream>>>(Wk + w512, qkvT + 512 * 512, 512, 512);
        k_wt<<<dim3(16, 16), 256, 0, stream>>>(Wv + w512, qkvT + 1024 * 512, 512, 512);
        k_wt<<<dim3(16, 16), 256, 0, stream>>>(Wo + w512, woT, 512, 512);
        k_wt<<<dim3(128, 16), 256, 0, stream>>>(W1 + (size_t)l * 512 * 4096, w1T, 512, 4096);
        k_wt<<<dim3(16, 64), 256, 0, stream>>>(W2 + (size_t)l * 2048 * 512, w2T, 2048, 512);

        k_ln<1, 0><<<BB, 256, 0, stream>>>(x2, nullptr, ln1g + l * DIMM, ln1b + l * DIMM, xs);
        k_mm<1, 0, 0><<<dim3(RT, 12), 256, 0, stream>>>(xs, qkvT, nullptr, nullptr, qkv, 512, 512, 512, 1536);
        k_attng<<<dim3(BB, GHH), 256, 0, stream>>>(qkv, proj + (size_t)l * MF * DHH, xs);
        k_attnl<<<dim3(BB, NH - GHH), 256, 0, stream>>>(qkv, xs);
        k_mm<0, 1, 1><<<dim3(RT, 4), 256, 0, stream>>>(xs, woT, bo + l * DIMM, x1, x1, 512, 512, 512, 512);
        k_ln<1, 0><<<BB, 256, 0, stream>>>(x1, nullptr, ln2g + l * DIMM, ln2b + l * DIMM, xs);
        // GLU chunk 0: hidden cols 0..1023 (a), 2048..3071 (g)
        k_glu<<<dim3(RT, 8), 256, 0, stream>>>(xs, w1T, w1T + (size_t)2048 * 512,
                                               b1 + (size_t)l * 4096, b1 + (size_t)l * 4096 + 2048, ub);
        k_mm<0, 1, 1><<<dim3(RT, 4), 256, 0, stream>>>(ub, w2T, b2 + l * DIMM, x2, x2, 1024, 2048, 1024, 512);
        // GLU chunk 1: hidden cols 1024..2047 (a), 3072..4095 (g)
        k_glu<<<dim3(RT, 8), 256, 0, stream>>>(xs, w1T + (size_t)1024 * 512, w1T + (size_t)3072 * 512,
                                               b1 + (size_t)l * 4096 + 1024, b1 + (size_t)l * 4096 + 3072, ub);
        k_mm<0, 0, 1><<<dim3(RT, 4), 256, 0, stream>>>(ub, w2T + 1024, nullptr, x2, x2, 1024, 2048, 1024, 512);
    }

    k_ln<0, 1><<<BB, 256, 0, stream>>>(x1, x2, lnfg, lnfb, xs);
    k_wt<<<dim3(32, 16), 256, 0, stream>>>(Wout, woutT, 512, 1024);
    k_mm<0, 1, 0><<<dim3(RT, 8), 256, 0, stream>>>(xs, woutT, bout, nullptr, logits, 512, 512, 512, 1024);
    k_head<<<BB, 256, 0, stream>>>(logits, Wl1, bl1, Wl2, bl2, outp);
}

// Round 4
// 9754.140 us; speedup vs baseline: 4.4729x; 1.2909x over previous
//
#include <hip/hip_runtime.h>
#include <math.h>

#define BB 2048
#define NN 15
#define DIMM 512
#define NH 8
#define GHH 4
#define DHH 64
#define MF 256
#define NLAYERS 12
#define NVOCAB 1024
#define ROWS (BB*NN)          // 30720
#define RT (ROWS/128)         // 240 row tiles

typedef __attribute__((ext_vector_type(8))) short s8b;
typedef __attribute__((ext_vector_type(4))) short s4b;
typedef __attribute__((ext_vector_type(4))) float f4;
typedef unsigned short ushort;
typedef unsigned int uint;

__device__ __forceinline__ ushort f2b(float f) {
    uint u = __builtin_bit_cast(uint, f);
    u = u + 0x7FFF + ((u >> 16) & 1);
    return (ushort)(u >> 16);
}
__device__ __forceinline__ float b2f(ushort b) {
    return __builtin_bit_cast(float, (uint)b << 16);
}
__device__ __forceinline__ void gll16(const ushort* g, ushort* l) {
    __builtin_amdgcn_global_load_lds(
        (const __attribute__((address_space(1))) uint*)g,
        (__attribute__((address_space(3))) uint*)l, 16, 0, 0);
}

// ---------------------------------------------------------------- embed
__global__ __launch_bounds__(256) void k_embed(const int* __restrict__ xm,
                                               const float* __restrict__ emb,
                                               float* __restrict__ x1,
                                               float* __restrict__ x2) {
    int idx = blockIdx.x * 256 + threadIdx.x;
    int row = idx >> 9;
    int d   = idx & 511;
    int n   = row % NN;
    int tok = xm[row];
    int j   = d & 255;
    float invf = expf(-(float)j * (9.2103403720f / 256.f));
    float arg  = (float)n * invf;
    float pe   = (d < 256) ? sinf(arg) : cosf(arg);
    float val  = emb[tok * DIMM + d] + pe;
    x1[idx] = val;
    x2[idx] = val;
}

// ---------------------------------------------------------------- layernorm (+optional add)(+pre_shift), bf16 out
template<int SHIFT, int ADD>
__global__ __launch_bounds__(256) void k_ln(const float* __restrict__ src,
                                            const float* __restrict__ src2,
                                            const float* __restrict__ gg,
                                            const float* __restrict__ bb,
                                            ushort* __restrict__ dst) {
    __shared__ float buf[NN][DIMM];
    int b    = blockIdx.x;
    int tid  = threadIdx.x;
    int wid  = tid >> 6;
    int lane = tid & 63;

    for (int n = wid; n < NN; n += 4) {
        size_t base = ((size_t)(b * NN + n)) * DIMM;
        float4 v0 = *(const float4*)(src + base + lane * 8);
        float4 v1 = *(const float4*)(src + base + lane * 8 + 4);
        if (ADD) {
            float4 w0 = *(const float4*)(src2 + base + lane * 8);
            float4 w1 = *(const float4*)(src2 + base + lane * 8 + 4);
            v0.x += w0.x; v0.y += w0.y; v0.z += w0.z; v0.w += w0.w;
            v1.x += w1.x; v1.y += w1.y; v1.z += w1.z; v1.w += w1.w;
        }
        float s = v0.x + v0.y + v0.z + v0.w + v1.x + v1.y + v1.z + v1.w;
        #pragma unroll
        for (int m = 1; m < 64; m <<= 1) s += __shfl_xor(s, m);
        float mu = s * (1.f / DIMM);
        float a0 = v0.x - mu, a1 = v0.y - mu, a2 = v0.z - mu, a3 = v0.w - mu;
        float a4 = v1.x - mu, a5 = v1.y - mu, a6 = v1.z - mu, a7 = v1.w - mu;
        float s2 = a0*a0 + a1*a1 + a2*a2 + a3*a3 + a4*a4 + a5*a5 + a6*a6 + a7*a7;
        #pragma unroll
        for (int m = 1; m < 64; m <<= 1) s2 += __shfl_xor(s2, m);
        float rstd = 1.f / sqrtf(s2 * (1.f / DIMM) + 1e-5f);
        float o[8] = {a0, a1, a2, a3, a4, a5, a6, a7};
        int d0 = lane * 8;
        #pragma unroll
        for (int i = 0; i < 8; ++i) {
            float val = o[i] * rstd * gg[d0 + i] + bb[d0 + i];
            if (SHIFT) buf[n][d0 + i] = val;
            else       dst[base + d0 + i] = f2b(val);
        }
    }
    if (SHIFT) {
        __syncthreads();
        for (int idx = tid; idx < NN * DIMM; idx += 256) {
            int n = idx >> 9, d = idx & 511;
            float val;
            if (d < 170)      val = (n < NN - 1) ? buf[n + 1][d] : 0.f;
            else if (d < 340) val = buf[n][d];
            else if (d < 510) val = (n > 0) ? buf[n - 1][d] : 0.f;
            else              val = buf[n][d];
            dst[((size_t)(b * NN + n)) * DIMM + d] = f2b(val);
        }
    }
}

// ---------------------------------------------------------------- weight transpose fp32[K][N] -> bf16[N][K]
__global__ __launch_bounds__(256) void k_wt(const float* __restrict__ src,
                                            ushort* __restrict__ dst, int K, int N) {
    __shared__ float t[32][33];
    int n0 = blockIdx.x * 32, k0 = blockIdx.y * 32;
    int tx = threadIdx.x & 31, ty = threadIdx.x >> 5;
    #pragma unroll
    for (int i = 0; i < 32; i += 8)
        t[ty + i][tx] = src[(size_t)(k0 + ty + i) * N + n0 + tx];
    __syncthreads();
    #pragma unroll
    for (int i = 0; i < 32; i += 8)
        dst[(size_t)(n0 + ty + i) * K + k0 + tx] = f2b(t[tx][ty + i]);
}

// ---------------------------------------------------------------- proj fp32 -> bf16 (all layers)
__global__ __launch_bounds__(256) void k_projcvt(const float* __restrict__ src,
                                                 ushort* __restrict__ dst, int n) {
    int i = blockIdx.x * 256 + threadIdx.x;
    if (i < n) dst[i] = f2b(src[i]);
}

// ---------------------------------------------------------------- bf16 MFMA GEMM: out = A[M,K](bf16) @ Bt[N,K](bf16)^T
template<int OUTB, int BIAS, int RES>
__global__ __launch_bounds__(256) void k_mm(const ushort* __restrict__ A,
                                            const ushort* __restrict__ Bt,
                                            const float* __restrict__ bias,
                                            const float* __restrict__ res,
                                            void* __restrict__ outv,
                                            int lda, int ldb, int K, int ldo) {
    __shared__ ushort smA[128 * 32];
    __shared__ ushort smB[128 * 32];
    int tid = threadIdx.x, wid = tid >> 6, lane = tid & 63;
    int row0 = blockIdx.x * 128, col0 = blockIdx.y * 128;
    int trow = tid >> 2, tkk = (tid & 3) * 8;
    f4 acc[4][4] = {};
    int rw = (wid >> 1) * 64, cw = (wid & 1) * 64;

    for (int k0 = 0; k0 < K; k0 += 32) {
        #pragma unroll
        for (int r = 0; r < 2; ++r) {
            gll16(A  + (size_t)(row0 + r * 64 + trow) * lda + k0 + tkk, smA + (r * 256 + wid * 64) * 8);
            gll16(Bt + (size_t)(col0 + r * 64 + trow) * ldb + k0 + tkk, smB + (r * 256 + wid * 64) * 8);
        }
        __syncthreads();
        s8b af[4], bf[4];
        #pragma unroll
        for (int m = 0; m < 4; ++m)
            af[m] = *(const s8b*)(smA + (rw + m * 16 + (lane & 15)) * 32 + (lane >> 4) * 8);
        #pragma unroll
        for (int n = 0; n < 4; ++n)
            bf[n] = *(const s8b*)(smB + (cw + n * 16 + (lane & 15)) * 32 + (lane >> 4) * 8);
        #pragma unroll
        for (int m = 0; m < 4; ++m)
            #pragma unroll
            for (int n = 0; n < 4; ++n)
                acc[m][n] = __builtin_amdgcn_mfma_f32_16x16x32_bf16(af[m], bf[n], acc[m][n], 0, 0, 0);
        __syncthreads();
    }
    #pragma unroll
    for (int m = 0; m < 4; ++m) {
        #pragma unroll
        for (int n = 0; n < 4; ++n) {
            int c = col0 + cw + n * 16 + (lane & 15);
            #pragma unroll
            for (int j = 0; j < 4; ++j) {
                int r = row0 + rw + m * 16 + (lane >> 4) * 4 + j;
                float v = acc[m][n][j];
                if (BIAS) v += bias[c];
                if (RES)  v += res[(size_t)r * ldo + c];
                if (OUTB) ((ushort*)outv)[(size_t)r * ldo + c] = f2b(v);
                else      ((float*)outv)[(size_t)r * ldo + c] = v;
            }
        }
    }
}

// ---------------------------------------------------------------- GLU FF1 MFMA: out = gelu(A@Wa+ba)*(A@Wg+bg), bf16 out
__global__ __launch_bounds__(256) void k_glu(const ushort* __restrict__ A,
                                             const ushort* __restrict__ Ba,
                                             const ushort* __restrict__ Bg,
                                             const float* __restrict__ ba,
                                             const float* __restrict__ bg,
                                             ushort* __restrict__ outp) {
    __shared__ ushort smA[128 * 32];
    __shared__ ushort smBa[128 * 32];
    __shared__ ushort smBg[128 * 32];
    int tid = threadIdx.x, wid = tid >> 6, lane = tid & 63;
    int row0 = blockIdx.x * 128, col0 = blockIdx.y * 128;
    int trow = tid >> 2, tkk = (tid & 3) * 8;
    f4 acca[4][4] = {}, accg[4][4] = {};
    int rw = (wid >> 1) * 64, cw = (wid & 1) * 64;

    for (int k0 = 0; k0 < 512; k0 += 32) {
        #pragma unroll
        for (int r = 0; r < 2; ++r) {
            gll16(A  + (size_t)(row0 + r * 64 + trow) * 512 + k0 + tkk, smA  + (r * 256 + wid * 64) * 8);
            gll16(Ba + (size_t)(col0 + r * 64 + trow) * 512 + k0 + tkk, smBa + (r * 256 + wid * 64) * 8);
            gll16(Bg + (size_t)(col0 + r * 64 + trow) * 512 + k0 + tkk, smBg + (r * 256 + wid * 64) * 8);
        }
        __syncthreads();
        s8b af[4], bfa[4], bfg[4];
        #pragma unroll
        for (int m = 0; m < 4; ++m)
            af[m] = *(const s8b*)(smA + (rw + m * 16 + (lane & 15)) * 32 + (lane >> 4) * 8);
        #pragma unroll
        for (int n = 0; n < 4; ++n) {
            bfa[n] = *(const s8b*)(smBa + (cw + n * 16 + (lane & 15)) * 32 + (lane >> 4) * 8);
            bfg[n] = *(const s8b*)(smBg + (cw + n * 16 + (lane & 15)) * 32 + (lane >> 4) * 8);
        }
        #pragma unroll
        for (int m = 0; m < 4; ++m)
            #pragma unroll
            for (int n = 0; n < 4; ++n) {
                acca[m][n] = __builtin_amdgcn_mfma_f32_16x16x32_bf16(af[m], bfa[n], acca[m][n], 0, 0, 0);
                accg[m][n] = __builtin_amdgcn_mfma_f32_16x16x32_bf16(af[m], bfg[n], accg[m][n], 0, 0, 0);
            }
        __syncthreads();
    }
    #pragma unroll
    for (int m = 0; m < 4; ++m) {
        #pragma unroll
        for (int n = 0; n < 4; ++n) {
            int c = col0 + cw + n * 16 + (lane & 15);
            float biasa = ba[c], biasg = bg[c];
            #pragma unroll
            for (int j = 0; j < 4; ++j) {
                int r = row0 + rw + m * 16 + (lane >> 4) * 4 + j;
                float a = acca[m][n][j] + biasa;
                float g = accg[m][n][j] + biasg;
                float ge = 0.5f * a * (1.f + erff(a * 0.70710678118f));
                outp[(size_t)r * 1024 + c] = f2b(ge * g);
            }
        }
    }
}

// ---------------------------------------------------------------- global-head attention (performer) via MFMA
// block = 256 thr (4 waves) per (b,h). wave w owns proj m-tiles 4w..4w+3; PV e-tile w.
__global__ __launch_bounds__(256) void k_attng(const ushort* __restrict__ qkv,
                                               const ushort* __restrict__ projb,
                                               ushort* __restrict__ outp) {
    __shared__ ushort sxq[16][72];      // rotated q bf16, row15 zero, padded stride
    __shared__ ushort sxk[16][72];
    __shared__ ushort sVT[64][40];      // V^T (e-major), cols>=15 zero
    __shared__ ushort sqp[16][264];     // qp features bf16
    __shared__ ushort skp[16][264];
    __shared__ ushort sA[16][40];       // scores bf16, cols>=15 zero
    __shared__ float sdq[16], sdk[16], sdinv[16];
    __shared__ float sPq[4][16];
    __shared__ float sPk[4];
    int b = blockIdx.x, h = blockIdx.y;
    int tid = threadIdx.x, w = tid >> 6, l = tid & 63;
    int i16 = l & 15, g = l >> 4;
    const ushort* basep = qkv + (size_t)b * NN * 1536 + h * 64;

    {   // zero pads
        uint* z1 = (uint*)&sVT[0][0];
        for (int i = tid; i < 1280; i += 256) z1[i] = 0;
        uint* z2 = (uint*)&sA[0][0];
        for (int i = tid; i < 320; i += 256) z2[i] = 0;
        if (tid < 64) { sxq[15][tid] = 0; sxk[15][tid] = 0; }
    }
    __syncthreads();
    // load + GPT-J rotary; V transposed
    for (int idx = tid; idx < NN * 32; idx += 256) {
        int n = idx >> 5, i = idx & 31;
        float invf = expf(-(float)i * (9.2103403720f / 32.f));
        float cc = cosf((float)n * invf), ss = sinf((float)n * invf);
        float q0 = b2f(basep[n * 1536 + 2 * i]), q1 = b2f(basep[n * 1536 + 2 * i + 1]);
        sxq[n][2 * i]     = f2b(q0 * cc - q1 * ss);
        sxq[n][2 * i + 1] = f2b(q1 * cc + q0 * ss);
        float k0 = b2f(basep[n * 1536 + 512 + 2 * i]), k1 = b2f(basep[n * 1536 + 512 + 2 * i + 1]);
        sxk[n][2 * i]     = f2b(k0 * cc - k1 * ss);
        sxk[n][2 * i + 1] = f2b(k1 * cc + k0 * ss);
    }
    for (int idx = tid; idx < NN * 64; idx += 256) {
        int n = idx >> 6, e = idx & 63;
        sVT[e][n] = basep[n * 1536 + 1024 + e];
    }
    __syncthreads();
    // diag (wave 0): 0.5*dn^2*||x||^2 per row
    if (w == 0) {
        int n = l >> 2, c = l & 3;
        float sa = 0.f, sb = 0.f;
        #pragma unroll
        for (int s = 0; s < 2; ++s) {
            s8b vq = *(const s8b*)&sxq[n][c * 16 + s * 8];
            s8b vk = *(const s8b*)&sxk[n][c * 16 + s * 8];
            #pragma unroll
            for (int j = 0; j < 8; ++j) {
                float x = b2f((ushort)vq[j]); sa += x * x;
                float y = b2f((ushort)vk[j]); sb += y * y;
            }
        }
        sa += __shfl_xor(sa, 1); sa += __shfl_xor(sa, 2);
        sb += __shfl_xor(sb, 1); sb += __shfl_xor(sb, 2);
        if (c == 0) { sdq[n] = 0.0625f * sa; sdk[n] = 0.0625f * sb; }
    }
    // dash MFMA: D[m][n] = sum_d proj[m][d]*x[n][d] (unscaled)
    s8b bq[2], bk[2];
    bq[0] = *(const s8b*)&sxq[i16][g * 8];
    bq[1] = *(const s8b*)&sxq[i16][32 + g * 8];
    bk[0] = *(const s8b*)&sxk[i16][g * 8];
    bk[1] = *(const s8b*)&sxk[i16][32 + g * 8];
    f4 accq[4] = {}, acck[4] = {};
    const ushort* pb = projb + (size_t)(w * 64 + i16) * 64 + g * 8;
    #pragma unroll
    for (int mi = 0; mi < 4; ++mi) {
        #pragma unroll
        for (int ks = 0; ks < 2; ++ks) {
            s8b a = *(const s8b*)(pb + mi * 16 * 64 + ks * 32);
            accq[mi] = __builtin_amdgcn_mfma_f32_16x16x32_bf16(a, bq[ks], accq[mi], 0, 0, 0);
            acck[mi] = __builtin_amdgcn_mfma_f32_16x16x32_bf16(a, bk[ks], acck[mi], 0, 0, 0);
        }
    }
    // maxes: per-row (q), global over n<15,m (k); lane holds col n=i16, rows m
    float mq = -1e30f, mkv = -1e30f;
    #pragma unroll
    for (int mi = 0; mi < 4; ++mi)
        #pragma unroll
        for (int j = 0; j < 4; ++j) {
            mq  = fmaxf(mq, accq[mi][j]);
            mkv = fmaxf(mkv, acck[mi][j]);
        }
    if (i16 == 15) mkv = -1e30f;
    mq = fmaxf(mq, __shfl_xor(mq, 16));
    mq = fmaxf(mq, __shfl_xor(mq, 32));
    #pragma unroll
    for (int m = 1; m < 64; m <<= 1) mkv = fmaxf(mkv, __shfl_xor(mkv, m));
    if (l < 16) sPq[w][l] = mq;
    if (l == 0) sPk[w] = mkv;
    __syncthreads();
    float mxq = fmaxf(fmaxf(sPq[0][i16], sPq[1][i16]), fmaxf(sPq[2][i16], sPq[3][i16]));
    float mxk = fmaxf(fmaxf(sPk[0], sPk[1]), fmaxf(sPk[2], sPk[3]));
    // qp/kp features -> LDS bf16
    const float dn = 0.35355339059f;   // 64^-0.25
    float dgq = sdq[i16], dgk = sdk[i16];
    #pragma unroll
    for (int mi = 0; mi < 4; ++mi) {
        s4b pq, pk;
        #pragma unroll
        for (int j = 0; j < 4; ++j) {
            float vq = 0.0625f * (expf(dn * (accq[mi][j] - mxq) - dgq) + 1e-4f);
            float vk = 0.0625f * (expf(dn * (acck[mi][j] - mxk) - dgk) + 1e-4f);
            pq[j] = (short)f2b(vq);
            pk[j] = (short)f2b(vk);
        }
        int m0 = (w * 4 + mi) * 16 + g * 4;
        *(s4b*)&sqp[i16][m0] = pq;
        *(s4b*)&skp[i16][m0] = pk;
    }
    __syncthreads();
    // scores A = qp @ kp^T (wave 0), rowsum -> d_inv; col 15 masked
    if (w == 0) {
        f4 accA = {};
        #pragma unroll
        for (int ks = 0; ks < 8; ++ks) {
            s8b aq = *(const s8b*)&sqp[i16][ks * 32 + g * 8];
            s8b ak = *(const s8b*)&skp[i16][ks * 32 + g * 8];
            accA = __builtin_amdgcn_mfma_f32_16x16x32_bf16(aq, ak, accA, 0, 0, 0);
        }
        #pragma unroll
        for (int j = 0; j < 4; ++j) {
            float v = (i16 == 15) ? 0.f : accA[j];
            float s = v;
            s += __shfl_xor(s, 1); s += __shfl_xor(s, 2);
            s += __shfl_xor(s, 4); s += __shfl_xor(s, 8);
            sA[g * 4 + j][i16] = f2b(v);
            if (i16 == 0) sdinv[g * 4 + j] = 1.f / s;
        }
    }
    __syncthreads();
    // PV: wave w does e-tile w
    {
        s8b aA = *(const s8b*)&sA[i16][g * 8];
        s8b bV = *(const s8b*)&sVT[w * 16 + i16][g * 8];
        f4 z = {};
        f4 o = __builtin_amdgcn_mfma_f32_16x16x32_bf16(aA, bV, z, 0, 0, 0);
        #pragma unroll
        for (int j = 0; j < 4; ++j) {
            int n = g * 4 + j;
            if (n < NN)
                outp[((size_t)(b * NN + n)) * DIMM + h * 64 + w * 16 + i16] = f2b(o[j] * sdinv[n]);
        }
    }
}

// ---------------------------------------------------------------- local-head attention (softmax) via MFMA, 1 wave
__global__ __launch_bounds__(64) void k_attnl(const ushort* __restrict__ qkv,
                                              ushort* __restrict__ outp) {
    __shared__ ushort sxq[16][72];
    __shared__ ushort sxk[16][72];
    __shared__ ushort sVT[64][40];
    __shared__ ushort sA[16][40];
    __shared__ float sdinv[16];
    int b = blockIdx.x, h = blockIdx.y + GHH;
    int l = threadIdx.x;
    int i16 = l & 15, g = l >> 4;
    const ushort* basep = qkv + (size_t)b * NN * 1536 + h * 64;

    {
        uint* z1 = (uint*)&sVT[0][0];
        for (int i = l; i < 1280; i += 64) z1[i] = 0;
        uint* z2 = (uint*)&sA[0][0];
        for (int i = l; i < 320; i += 64) z2[i] = 0;
        sxq[15][l] = 0; sxk[15][l] = 0;
    }
    __syncthreads();
    // NeoX rotary
    for (int idx = l; idx < NN * 32; idx += 64) {
        int n = idx >> 5, i = idx & 31;
        float invf = expf(-(float)i * (9.2103403720f / 32.f));
        float cc = cosf((float)n * invf), ss = sinf((float)n * invf);
        float qlo = b2f(basep[n * 1536 + i]), qhi = b2f(basep[n * 1536 + i + 32]);
        sxq[n][i]      = f2b(qlo * cc - qhi * ss);
        sxq[n][i + 32] = f2b(qhi * cc + qlo * ss);
        float klo = b2f(basep[n * 1536 + 512 + i]), khi = b2f(basep[n * 1536 + 512 + i + 32]);
        sxk[n][i]      = f2b(klo * cc - khi * ss);
        sxk[n][i + 32] = f2b(khi * cc + klo * ss);
    }
    for (int idx = l; idx < NN * 64; idx += 64) {
        int n = idx >> 6, e = idx & 63;
        sVT[e][n] = basep[n * 1536 + 1024 + e];
    }
    __syncthreads();
    // sim = q@k^T * 0.125
    f4 acc = {};
    #pragma unroll
    for (int ks = 0; ks < 2; ++ks) {
        s8b aq = *(const s8b*)&sxq[i16][ks * 32 + g * 8];
        s8b bk = *(const s8b*)&sxk[i16][ks * 32 + g * 8];
        acc = __builtin_amdgcn_mfma_f32_16x16x32_bf16(aq, bk, acc, 0, 0, 0);
    }
    // softmax rows (col j = i16; rows g*4+jj); col 15 masked
    #pragma unroll
    for (int j = 0; j < 4; ++j) {
        float v = (i16 == 15) ? -1e30f : acc[j] * 0.125f;
        float mx = v;
        mx = fmaxf(mx, __shfl_xor(mx, 1));
        mx = fmaxf(mx, __shfl_xor(mx, 2));
        mx = fmaxf(mx, __shfl_xor(mx, 4));
        mx = fmaxf(mx, __shfl_xor(mx, 8));
        float e = (i16 == 15) ? 0.f : expf(v - mx);
        float s = e;
        s += __shfl_xor(s, 1); s += __shfl_xor(s, 2);
        s += __shfl_xor(s, 4); s += __shfl_xor(s, 8);
        sA[g * 4 + j][i16] = f2b(e);
        if (i16 == 0) sdinv[g * 4 + j] = 1.f / s;
    }
    __syncthreads();
    // PV
    s8b aA = *(const s8b*)&sA[i16][g * 8];
    #pragma unroll
    for (int et = 0; et < 4; ++et) {
        s8b bV = *(const s8b*)&sVT[et * 16 + i16][g * 8];
        f4 z = {};
        f4 o = __builtin_amdgcn_mfma_f32_16x16x32_bf16(aA, bV, z, 0, 0, 0);
        #pragma unroll
        for (int j = 0; j < 4; ++j) {
            int n = g * 4 + j;
            if (n < NN)
                outp[((size_t)(b * NN + n)) * DIMM + h * 64 + et * 16 + i16] = f2b(o[j] * sdinv[n]);
        }
    }
}

// ---------------------------------------------------------------- final head
__global__ __launch_bounds__(256) void k_head(const float* __restrict__ logits,
                                              const float* __restrict__ Wl1,
                                              const float* __restrict__ bl1,
                                              const float* __restrict__ Wl2,
                                              const float* __restrict__ bl2,
                                              float* __restrict__ outp) {
    __shared__ float xa[NVOCAB];
    __shared__ float hh[64];
    int b = blockIdx.x, tid = threadIdx.x;
    for (int c = tid; c < NVOCAB; c += 256) {
        float s = 0.f;
        #pragma unroll
        for (int n = 0; n < NN; ++n) s += logits[((size_t)(b * NN + n)) * NVOCAB + c];
        xa[c] = s * (1.f / NN);
    }
    __syncthreads();
    if (tid < 64) {
        float s = bl1[tid];
        for (int kk = 0; kk < NVOCAB; ++kk) s += xa[kk] * Wl1[kk * 64 + tid];
        hh[tid] = fmaxf(s, 0.f);
    }
    __syncthreads();
    if (tid < 2) {
        float s = bl2[tid];
        #pragma unroll
        for (int j = 0; j < 64; ++j) s += hh[j] * Wl2[j * 2 + tid];
        outp[(size_t)b * 2 + tid] = s;
    }
}

// ---------------------------------------------------------------- host
extern "C" void kernel_launch(void* const* d_in, const int* in_sizes, int n_in,
                              void* d_out, int out_size, void* d_ws, size_t ws_size,
                              hipStream_t stream) {
    (void)in_sizes; (void)n_in; (void)out_size; (void)ws_size;
    const int*   x_mcc = (const int*)d_in[0];
    const float* emb   = (const float*)d_in[1];
    const float* ln1g  = (const float*)d_in[2];
    const float* ln1b  = (const float*)d_in[3];
    const float* Wq    = (const float*)d_in[4];
    const float* Wk    = (const float*)d_in[5];
    const float* Wv    = (const float*)d_in[6];
    const float* Wo    = (const float*)d_in[7];
    const float* bo    = (const float*)d_in[8];
    const float* proj  = (const float*)d_in[9];
    const float* ln2g  = (const float*)d_in[10];
    const float* ln2b  = (const float*)d_in[11];
    const float* W1    = (const float*)d_in[12];
    const float* b1    = (const float*)d_in[13];
    const float* W2    = (const float*)d_in[14];
    const float* b2    = (const float*)d_in[15];
    const float* lnfg  = (const float*)d_in[16];
    const float* lnfb  = (const float*)d_in[17];
    const float* Wout  = (const float*)d_in[18];
    const float* bout  = (const float*)d_in[19];
    const float* Wl1   = (const float*)d_in[20];
    const float* bl1   = (const float*)d_in[21];
    const float* Wl2   = (const float*)d_in[22];
    const float* bl2   = (const float*)d_in[23];
    float* outp = (float*)d_out;

    // ws layout (S = ROWS*512*4 = 62.9MB): x1(S) x2(S) xs(S/2,bf16) qkv(1.5S,bf16)
    //   ub(S,bf16 [30720][1024]) wbuf(~8.4MB). logits fp32 2S aliases qkv+ub.
    char* ws = (char*)d_ws;
    const size_t S = (size_t)ROWS * DIMM * 4;
    float*  x1   = (float*)(ws);
    float*  x2   = (float*)(ws + S);
    ushort* xs   = (ushort*)(ws + 2 * S);
    ushort* qkv  = (ushort*)(ws + 2 * S + S / 2);
    ushort* ub   = (ushort*)(ws + 4 * S);
    ushort* wb   = (ushort*)(ws + 5 * S);
    float*  logits = (float*)(ws + 2 * S + S / 2);
    ushort* qkvT = wb;                               // [1536][512]
    ushort* woT  = wb + 1536 * 512;                  // [512][512]
    ushort* w1T  = wb + 1536 * 512 + 512 * 512;      // [4096][512]
    ushort* w2T  = w1T + 4096 * 512;                 // [512][2048]
    ushort* projb = w2T + 512 * 2048;                // [12][256][64] bf16
    ushort* woutT = w1T;                             // [1024][512], reused at end

    k_embed<<<(ROWS * DIMM) / 256, 256, 0, stream>>>(x_mcc, emb, x1, x2);
    k_projcvt<<<(NLAYERS * MF * DHH) / 256, 256, 0, stream>>>(proj, projb, NLAYERS * MF * DHH);

    for (int l = 0; l < NLAYERS; ++l) {
        const size_t w512 = (size_t)l * 512 * 512;
        k_wt<<<dim3(16, 16), 256, 0, stream>>>(Wq + w512, qkvT,              512, 512);
        k_wt<<<dim3(16, 16), 256, 0, stream>>>(Wk + w512, qkvT + 512 * 512,  512, 512);
        k_wt<<<dim3(16, 16), 256, 0, stream>>>(Wv + w512, qkvT + 1024 * 512, 512, 512);
        k_wt<<<dim3(16, 16), 256, 0, stream>>>(Wo + w512, woT, 512, 512);
        k_wt<<<dim3(128, 16), 256, 0, stream>>>(W1 + (size_t)l * 512 * 4096, w1T, 512, 4096);
        k_wt<<<dim3(16, 64), 256, 0, stream>>>(W2 + (size_t)l * 2048 * 512, w2T, 2048, 512);

        k_ln<1, 0><<<BB, 256, 0, stream>>>(x2, nullptr, ln1g + l * DIMM, ln1b + l * DIMM, xs);
        k_mm<1, 0, 0><<<dim3(RT, 12), 256, 0, stream>>>(xs, qkvT, nullptr, nullptr, qkv, 512, 512, 512, 1536);
        k_attng<<<dim3(BB, GHH), 256, 0, stream>>>(qkv, projb + (size_t)l * MF * DHH, xs);
        k_attnl<<<dim3(BB, NH - GHH), 64, 0, stream>>>(qkv, xs);
        k_mm<0, 1, 1><<<dim3(RT, 4), 256, 0, stream>>>(xs, woT, bo + l * DIMM, x1, x1, 512, 512, 512, 512);
        k_ln<1, 0><<<BB, 256, 0, stream>>>(x1, nullptr, ln2g + l * DIMM, ln2b + l * DIMM, xs);
        // GLU chunk 0: hidden cols 0..1023 (a), 2048..3071 (g)
        k_glu<<<dim3(RT, 8), 256, 0, stream>>>(xs, w1T, w1T + (size_t)2048 * 512,
                                               b1 + (size_t)l * 4096, b1 + (size_t)l * 4096 + 2048, ub);
        k_mm<0, 1, 1><<<dim3(RT, 4), 256, 0, stream>>>(ub, w2T, b2 + l * DIMM, x2, x2, 1024, 2048, 1024, 512);
        // GLU chunk 1: hidden cols 1024..2047 (a), 3072..4095 (g)
        k_glu<<<dim3(RT, 8), 256, 0, stream>>>(xs, w1T + (size_t)1024 * 512, w1T + (size_t)3072 * 512,
                                               b1 + (size_t)l * 4096 + 1024, b1 + (size_t)l * 4096 + 3072, ub);
        k_mm<0, 0, 1><<<dim3(RT, 4), 256, 0, stream>>>(ub, w2T + 1024, nullptr, x2, x2, 1024, 2048, 1024, 512);
    }

    k_ln<0, 1><<<BB, 256, 0, stream>>>(x1, x2, lnfg, lnfb, xs);
    k_wt<<<dim3(32, 16), 256, 0, stream>>>(Wout, woutT, 512, 1024);
    k_mm<0, 1, 0><<<dim3(RT, 8), 256, 0, stream>>>(xs, woutT, bout, nullptr, logits, 512, 512, 512, 1024);
    k_head<<<BB, 256, 0, stream>>>(logits, Wl1, bl1, Wl2, bl2, outp);
}

// Round 6
// 8266.488 us; speedup vs baseline: 5.2778x; 1.1800x over previous
//
#include <hip/hip_runtime.h>
#include <math.h>

#define BB 2048
#define NN 15
#define DIMM 512
#define NH 8
#define GHH 4
#define DHH 64
#define MF 256
#define NLAYERS 12
#define NVOCAB 1024
#define ROWS (BB*NN)          // 30720
#define RT (ROWS/128)         // 240 row tiles

typedef __attribute__((ext_vector_type(8))) short s8b;
typedef __attribute__((ext_vector_type(4))) short s4b;
typedef __attribute__((ext_vector_type(4))) float f4;
typedef unsigned short ushort;
typedef unsigned int uint;

__device__ __forceinline__ ushort f2b(float f) {
    uint u = __builtin_bit_cast(uint, f);
    u = u + 0x7FFF + ((u >> 16) & 1);
    return (ushort)(u >> 16);
}
__device__ __forceinline__ float b2f(ushort b) {
    return __builtin_bit_cast(float, (uint)b << 16);
}
__device__ __forceinline__ void gll16(const ushort* g, ushort* l) {
    __builtin_amdgcn_global_load_lds(
        (const __attribute__((address_space(1))) uint*)g,
        (__attribute__((address_space(3))) uint*)l, 16, 0, 0);
}

// ---------------------------------------------------------------- embed
__global__ __launch_bounds__(256) void k_embed(const int* __restrict__ xm,
                                               const float* __restrict__ emb,
                                               float* __restrict__ x1,
                                               float* __restrict__ x2) {
    int idx = blockIdx.x * 256 + threadIdx.x;
    int row = idx >> 9;
    int d   = idx & 511;
    int n   = row % NN;
    int tok = xm[row];
    int j   = d & 255;
    float invf = expf(-(float)j * (9.2103403720f / 256.f));
    float arg  = (float)n * invf;
    float pe   = (d < 256) ? sinf(arg) : cosf(arg);
    float val  = emb[tok * DIMM + d] + pe;
    x1[idx] = val;
    x2[idx] = val;
}

// ---------------------------------------------------------------- layernorm (+optional add)(+pre_shift), bf16 out
template<int SHIFT, int ADD>
__global__ __launch_bounds__(256) void k_ln(const float* __restrict__ src,
                                            const float* __restrict__ src2,
                                            const float* __restrict__ gg,
                                            const float* __restrict__ bb,
                                            ushort* __restrict__ dst) {
    __shared__ float buf[NN][DIMM];
    int b    = blockIdx.x;
    int tid  = threadIdx.x;
    int wid  = tid >> 6;
    int lane = tid & 63;

    for (int n = wid; n < NN; n += 4) {
        size_t base = ((size_t)(b * NN + n)) * DIMM;
        float4 v0 = *(const float4*)(src + base + lane * 8);
        float4 v1 = *(const float4*)(src + base + lane * 8 + 4);
        if (ADD) {
            float4 w0 = *(const float4*)(src2 + base + lane * 8);
            float4 w1 = *(const float4*)(src2 + base + lane * 8 + 4);
            v0.x += w0.x; v0.y += w0.y; v0.z += w0.z; v0.w += w0.w;
            v1.x += w1.x; v1.y += w1.y; v1.z += w1.z; v1.w += w1.w;
        }
        float s = v0.x + v0.y + v0.z + v0.w + v1.x + v1.y + v1.z + v1.w;
        #pragma unroll
        for (int m = 1; m < 64; m <<= 1) s += __shfl_xor(s, m);
        float mu = s * (1.f / DIMM);
        float a0 = v0.x - mu, a1 = v0.y - mu, a2 = v0.z - mu, a3 = v0.w - mu;
        float a4 = v1.x - mu, a5 = v1.y - mu, a6 = v1.z - mu, a7 = v1.w - mu;
        float s2 = a0*a0 + a1*a1 + a2*a2 + a3*a3 + a4*a4 + a5*a5 + a6*a6 + a7*a7;
        #pragma unroll
        for (int m = 1; m < 64; m <<= 1) s2 += __shfl_xor(s2, m);
        float rstd = 1.f / sqrtf(s2 * (1.f / DIMM) + 1e-5f);
        float o[8] = {a0, a1, a2, a3, a4, a5, a6, a7};
        int d0 = lane * 8;
        #pragma unroll
        for (int i = 0; i < 8; ++i) {
            float val = o[i] * rstd * gg[d0 + i] + bb[d0 + i];
            if (SHIFT) buf[n][d0 + i] = val;
            else       dst[base + d0 + i] = f2b(val);
        }
    }
    if (SHIFT) {
        __syncthreads();
        for (int idx = tid; idx < NN * DIMM; idx += 256) {
            int n = idx >> 9, d = idx & 511;
            float val;
            if (d < 170)      val = (n < NN - 1) ? buf[n + 1][d] : 0.f;
            else if (d < 340) val = buf[n][d];
            else if (d < 510) val = (n > 0) ? buf[n - 1][d] : 0.f;
            else              val = buf[n][d];
            dst[((size_t)(b * NN + n)) * DIMM + d] = f2b(val);
        }
    }
}

// ---------------------------------------------------------------- weight transpose fp32[K][N] -> bf16[N][K]
__global__ __launch_bounds__(256) void k_wt(const float* __restrict__ src,
                                            ushort* __restrict__ dst, int K, int N) {
    __shared__ float t[32][33];
    int n0 = blockIdx.x * 32, k0 = blockIdx.y * 32;
    int tx = threadIdx.x & 31, ty = threadIdx.x >> 5;
    #pragma unroll
    for (int i = 0; i < 32; i += 8)
        t[ty + i][tx] = src[(size_t)(k0 + ty + i) * N + n0 + tx];
    __syncthreads();
    #pragma unroll
    for (int i = 0; i < 32; i += 8)
        dst[(size_t)(n0 + ty + i) * K + k0 + tx] = f2b(t[tx][ty + i]);
}

// ---------------------------------------------------------------- proj fp32 -> bf16 (all layers)
__global__ __launch_bounds__(256) void k_projcvt(const float* __restrict__ src,
                                                 ushort* __restrict__ dst, int n) {
    int i = blockIdx.x * 256 + threadIdx.x;
    if (i < n) dst[i] = f2b(src[i]);
}

// ---------------------------------------------------------------- bf16 MFMA GEMM: out = A[M,K](bf16) @ Bt[N,K](bf16)^T
// 128x64 tile, BK=32, 4 waves (2x2), per-wave 64x32 (4x2 frags = 32 AGPR),
// 2-phase double-buffer: STAGE(t+1) || compute(t); one barrier per K-step.
template<int OUTB, int BIAS, int RES>
__global__ __launch_bounds__(256, 3) void k_mm(const ushort* __restrict__ A,
                                               const ushort* __restrict__ Bt,
                                               const float* __restrict__ bias,
                                               const float* __restrict__ res,
                                               void* __restrict__ outv,
                                               int lda, int ldb, int K, int ldo) {
    __shared__ ushort smA[2][128 * 32];
    __shared__ ushort smB[2][64 * 32];
    int tid = threadIdx.x, wid = tid >> 6, lane = tid & 63;
    int i16 = lane & 15, g = lane >> 4;
    int row0 = blockIdx.x * 128, col0 = blockIdx.y * 64;
    int wr = wid >> 1, wc = wid & 1;
    f4 acc[4][2] = {};
    const int seg0 = wid * 64 + lane;      // A it0 / B
    const int seg1 = 256 + seg0;           // A it1
    const int NT = K >> 5;

    auto STAGE = [&](int c, int k0) {
        gll16(A  + (size_t)(row0 + (seg0 >> 2)) * lda + k0 + (seg0 & 3) * 8, &smA[c][(wid * 64) * 8]);
        gll16(A  + (size_t)(row0 + (seg1 >> 2)) * lda + k0 + (seg1 & 3) * 8, &smA[c][(256 + wid * 64) * 8]);
        gll16(Bt + (size_t)(col0 + (seg0 >> 2)) * ldb + k0 + (seg0 & 3) * 8, &smB[c][(wid * 64) * 8]);
    };

    STAGE(0, 0);
    __syncthreads();
    for (int t = 0; t < NT; ++t) {
        int cur = t & 1;
        if (t + 1 < NT) STAGE(cur ^ 1, (t + 1) * 32);
        s8b af[4], bf[2];
        #pragma unroll
        for (int m = 0; m < 4; ++m)
            af[m] = *(const s8b*)&smA[cur][(wr * 64 + m * 16 + i16) * 32 + g * 8];
        #pragma unroll
        for (int n = 0; n < 2; ++n)
            bf[n] = *(const s8b*)&smB[cur][(wc * 32 + n * 16 + i16) * 32 + g * 8];
        #pragma unroll
        for (int m = 0; m < 4; ++m)
            #pragma unroll
            for (int n = 0; n < 2; ++n)
                acc[m][n] = __builtin_amdgcn_mfma_f32_16x16x32_bf16(af[m], bf[n], acc[m][n], 0, 0, 0);
        __syncthreads();
    }
    #pragma unroll
    for (int m = 0; m < 4; ++m) {
        #pragma unroll
        for (int n = 0; n < 2; ++n) {
            int c = col0 + wc * 32 + n * 16 + i16;
            #pragma unroll
            for (int j = 0; j < 4; ++j) {
                int r = row0 + wr * 64 + m * 16 + g * 4 + j;
                float v = acc[m][n][j];
                if (BIAS) v += bias[c];
                if (RES)  v += res[(size_t)r * ldo + c];
                if (OUTB) ((ushort*)outv)[(size_t)r * ldo + c] = f2b(v);
                else      ((float*)outv)[(size_t)r * ldo + c] = v;
            }
        }
    }
}

// ---------------------------------------------------------------- GLU FF1 MFMA: out = gelu(A@Wa+ba)*(A@Wg+bg), bf16 out
// 128x64 tile, dual acc per-wave 64x32 (64 AGPR), 2-phase double-buffer.
__global__ __launch_bounds__(256, 2) void k_glu(const ushort* __restrict__ A,
                                                const ushort* __restrict__ Ba,
                                                const ushort* __restrict__ Bg,
                                                const float* __restrict__ ba,
                                                const float* __restrict__ bg,
                                                ushort* __restrict__ outp) {
    __shared__ ushort smA[2][128 * 32];
    __shared__ ushort smBa[2][64 * 32];
    __shared__ ushort smBg[2][64 * 32];
    int tid = threadIdx.x, wid = tid >> 6, lane = tid & 63;
    int i16 = lane & 15, g = lane >> 4;
    int row0 = blockIdx.x * 128, col0 = blockIdx.y * 64;
    int wr = wid >> 1, wc = wid & 1;
    f4 acca[4][2] = {}, accg[4][2] = {};
    const int seg0 = wid * 64 + lane;
    const int seg1 = 256 + seg0;

    auto STAGE = [&](int c, int k0) {
        gll16(A  + (size_t)(row0 + (seg0 >> 2)) * 512 + k0 + (seg0 & 3) * 8, &smA[c][(wid * 64) * 8]);
        gll16(A  + (size_t)(row0 + (seg1 >> 2)) * 512 + k0 + (seg1 & 3) * 8, &smA[c][(256 + wid * 64) * 8]);
        gll16(Ba + (size_t)(col0 + (seg0 >> 2)) * 512 + k0 + (seg0 & 3) * 8, &smBa[c][(wid * 64) * 8]);
        gll16(Bg + (size_t)(col0 + (seg0 >> 2)) * 512 + k0 + (seg0 & 3) * 8, &smBg[c][(wid * 64) * 8]);
    };

    STAGE(0, 0);
    __syncthreads();
    for (int t = 0; t < 16; ++t) {
        int cur = t & 1;
        if (t + 1 < 16) STAGE(cur ^ 1, (t + 1) * 32);
        s8b af[4], bfa[2], bfg[2];
        #pragma unroll
        for (int m = 0; m < 4; ++m)
            af[m] = *(const s8b*)&smA[cur][(wr * 64 + m * 16 + i16) * 32 + g * 8];
        #pragma unroll
        for (int n = 0; n < 2; ++n) {
            bfa[n] = *(const s8b*)&smBa[cur][(wc * 32 + n * 16 + i16) * 32 + g * 8];
            bfg[n] = *(const s8b*)&smBg[cur][(wc * 32 + n * 16 + i16) * 32 + g * 8];
        }
        #pragma unroll
        for (int m = 0; m < 4; ++m)
            #pragma unroll
            for (int n = 0; n < 2; ++n) {
                acca[m][n] = __builtin_amdgcn_mfma_f32_16x16x32_bf16(af[m], bfa[n], acca[m][n], 0, 0, 0);
                accg[m][n] = __builtin_amdgcn_mfma_f32_16x16x32_bf16(af[m], bfg[n], accg[m][n], 0, 0, 0);
            }
        __syncthreads();
    }
    #pragma unroll
    for (int m = 0; m < 4; ++m) {
        #pragma unroll
        for (int n = 0; n < 2; ++n) {
            int c = col0 + wc * 32 + n * 16 + i16;
            float biasa = ba[c], biasg = bg[c];
            #pragma unroll
            for (int j = 0; j < 4; ++j) {
                int r = row0 + wr * 64 + m * 16 + g * 4 + j;
                float a = acca[m][n][j] + biasa;
                float gg = accg[m][n][j] + biasg;
                float ge = 0.5f * a * (1.f + erff(a * 0.70710678118f));
                outp[(size_t)r * 1024 + c] = f2b(ge * gg);
            }
        }
    }
}

// ---------------------------------------------------------------- global-head attention (performer) via MFMA
__global__ __launch_bounds__(256) void k_attng(const ushort* __restrict__ qkv,
                                               const ushort* __restrict__ projb,
                                               ushort* __restrict__ outp) {
    __shared__ ushort sxq[16][72];      // rotated q bf16, row15 zero, padded stride
    __shared__ ushort sxk[16][72];
    __shared__ ushort sVT[64][40];      // V^T (e-major), cols>=15 zero
    __shared__ ushort sqp[16][264];     // qp features bf16
    __shared__ ushort skp[16][264];
    __shared__ ushort sA[16][40];       // scores bf16, cols>=15 zero
    __shared__ float sdq[16], sdk[16], sdinv[16];
    __shared__ float sPq[4][16];
    __shared__ float sPk[4];
    int b = blockIdx.x, h = blockIdx.y;
    int tid = threadIdx.x, w = tid >> 6, l = tid & 63;
    int i16 = l & 15, g = l >> 4;
    const ushort* basep = qkv + (size_t)b * NN * 1536 + h * 64;

    {   // zero pads
        uint* z1 = (uint*)&sVT[0][0];
        for (int i = tid; i < 1280; i += 256) z1[i] = 0;
        uint* z2 = (uint*)&sA[0][0];
        for (int i = tid; i < 320; i += 256) z2[i] = 0;
        if (tid < 64) { sxq[15][tid] = 0; sxk[15][tid] = 0; }
    }
    __syncthreads();
    // load + GPT-J rotary; V transposed
    for (int idx = tid; idx < NN * 32; idx += 256) {
        int n = idx >> 5, i = idx & 31;
        float invf = expf(-(float)i * (9.2103403720f / 32.f));
        float cc = cosf((float)n * invf), ss = sinf((float)n * invf);
        float q0 = b2f(basep[n * 1536 + 2 * i]), q1 = b2f(basep[n * 1536 + 2 * i + 1]);
        sxq[n][2 * i]     = f2b(q0 * cc - q1 * ss);
        sxq[n][2 * i + 1] = f2b(q1 * cc + q0 * ss);
        float k0 = b2f(basep[n * 1536 + 512 + 2 * i]), k1 = b2f(basep[n * 1536 + 512 + 2 * i + 1]);
        sxk[n][2 * i]     = f2b(k0 * cc - k1 * ss);
        sxk[n][2 * i + 1] = f2b(k1 * cc + k0 * ss);
    }
    for (int idx = tid; idx < NN * 64; idx += 256) {
        int n = idx >> 6, e = idx & 63;
        sVT[e][n] = basep[n * 1536 + 1024 + e];
    }
    __syncthreads();
    // diag (wave 0): 0.5*dn^2*||x||^2 per row
    if (w == 0) {
        int n = l >> 2, c = l & 3;
        float sa = 0.f, sb = 0.f;
        #pragma unroll
        for (int s = 0; s < 2; ++s) {
            s8b vq = *(const s8b*)&sxq[n][c * 16 + s * 8];
            s8b vk = *(const s8b*)&sxk[n][c * 16 + s * 8];
            #pragma unroll
            for (int j = 0; j < 8; ++j) {
                float x = b2f((ushort)vq[j]); sa += x * x;
                float y = b2f((ushort)vk[j]); sb += y * y;
            }
        }
        sa += __shfl_xor(sa, 1); sa += __shfl_xor(sa, 2);
        sb += __shfl_xor(sb, 1); sb += __shfl_xor(sb, 2);
        if (c == 0) { sdq[n] = 0.0625f * sa; sdk[n] = 0.0625f * sb; }
    }
    // dash MFMA: D[m][n] = sum_d proj[m][d]*x[n][d] (unscaled)
    s8b bq[2], bk[2];
    bq[0] = *(const s8b*)&sxq[i16][g * 8];
    bq[1] = *(const s8b*)&sxq[i16][32 + g * 8];
    bk[0] = *(const s8b*)&sxk[i16][g * 8];
    bk[1] = *(const s8b*)&sxk[i16][32 + g * 8];
    f4 accq[4] = {}, acck[4] = {};
    const ushort* pb = projb + (size_t)(w * 64 + i16) * 64 + g * 8;
    #pragma unroll
    for (int mi = 0; mi < 4; ++mi) {
        #pragma unroll
        for (int ks = 0; ks < 2; ++ks) {
            s8b a = *(const s8b*)(pb + mi * 16 * 64 + ks * 32);
            accq[mi] = __builtin_amdgcn_mfma_f32_16x16x32_bf16(a, bq[ks], accq[mi], 0, 0, 0);
            acck[mi] = __builtin_amdgcn_mfma_f32_16x16x32_bf16(a, bk[ks], acck[mi], 0, 0, 0);
        }
    }
    // maxes: per-row (q), global over n<15,m (k)
    float mq = -1e30f, mkv = -1e30f;
    #pragma unroll
    for (int mi = 0; mi < 4; ++mi)
        #pragma unroll
        for (int j = 0; j < 4; ++j) {
            mq  = fmaxf(mq, accq[mi][j]);
            mkv = fmaxf(mkv, acck[mi][j]);
        }
    if (i16 == 15) mkv = -1e30f;
    mq = fmaxf(mq, __shfl_xor(mq, 16));
    mq = fmaxf(mq, __shfl_xor(mq, 32));
    #pragma unroll
    for (int m = 1; m < 64; m <<= 1) mkv = fmaxf(mkv, __shfl_xor(mkv, m));
    if (l < 16) sPq[w][l] = mq;
    if (l == 0) sPk[w] = mkv;
    __syncthreads();
    float mxq = fmaxf(fmaxf(sPq[0][i16], sPq[1][i16]), fmaxf(sPq[2][i16], sPq[3][i16]));
    float mxk = fmaxf(fmaxf(sPk[0], sPk[1]), fmaxf(sPk[2], sPk[3]));
    // qp/kp features -> LDS bf16
    const float dn = 0.35355339059f;   // 64^-0.25
    float dgq = sdq[i16], dgk = sdk[i16];
    #pragma unroll
    for (int mi = 0; mi < 4; ++mi) {
        s4b pq, pk;
        #pragma unroll
        for (int j = 0; j < 4; ++j) {
            float vq = 0.0625f * (expf(dn * (accq[mi][j] - mxq) - dgq) + 1e-4f);
            float vk = 0.0625f * (expf(dn * (acck[mi][j] - mxk) - dgk) + 1e-4f);
            pq[j] = (short)f2b(vq);
            pk[j] = (short)f2b(vk);
        }
        int m0 = (w * 4 + mi) * 16 + g * 4;
        *(s4b*)&sqp[i16][m0] = pq;
        *(s4b*)&skp[i16][m0] = pk;
    }
    __syncthreads();
    // scores A = qp @ kp^T (wave 0), rowsum -> d_inv; col 15 masked
    if (w == 0) {
        f4 accA = {};
        #pragma unroll
        for (int ks = 0; ks < 8; ++ks) {
            s8b aq = *(const s8b*)&sqp[i16][ks * 32 + g * 8];
            s8b ak = *(const s8b*)&skp[i16][ks * 32 + g * 8];
            accA = __builtin_amdgcn_mfma_f32_16x16x32_bf16(aq, ak, accA, 0, 0, 0);
        }
        #pragma unroll
        for (int j = 0; j < 4; ++j) {
            float v = (i16 == 15) ? 0.f : accA[j];
            float s = v;
            s += __shfl_xor(s, 1); s += __shfl_xor(s, 2);
            s += __shfl_xor(s, 4); s += __shfl_xor(s, 8);
            sA[g * 4 + j][i16] = f2b(v);
            if (i16 == 0) sdinv[g * 4 + j] = 1.f / s;
        }
    }
    __syncthreads();
    // PV: wave w does e-tile w
    {
        s8b aA = *(const s8b*)&sA[i16][g * 8];
        s8b bV = *(const s8b*)&sVT[w * 16 + i16][g * 8];
        f4 z = {};
        f4 o = __builtin_amdgcn_mfma_f32_16x16x32_bf16(aA, bV, z, 0, 0, 0);
        #pragma unroll
        for (int j = 0; j < 4; ++j) {
            int n = g * 4 + j;
            if (n < NN)
                outp[((size_t)(b * NN + n)) * DIMM + h * 64 + w * 16 + i16] = f2b(o[j] * sdinv[n]);
        }
    }
}

// ---------------------------------------------------------------- local-head attention (softmax) via MFMA, 1 wave
__global__ __launch_bounds__(64) void k_attnl(const ushort* __restrict__ qkv,
                                              ushort* __restrict__ outp) {
    __shared__ ushort sxq[16][72];
    __shared__ ushort sxk[16][72];
    __shared__ ushort sVT[64][40];
    __shared__ ushort sA[16][40];
    __shared__ float sdinv[16];
    int b = blockIdx.x, h = blockIdx.y + GHH;
    int l = threadIdx.x;
    int i16 = l & 15, g = l >> 4;
    const ushort* basep = qkv + (size_t)b * NN * 1536 + h * 64;

    {
        uint* z1 = (uint*)&sVT[0][0];
        for (int i = l; i < 1280; i += 64) z1[i] = 0;
        uint* z2 = (uint*)&sA[0][0];
        for (int i = l; i < 320; i += 64) z2[i] = 0;
        sxq[15][l] = 0; sxk[15][l] = 0;
    }
    __syncthreads();
    // NeoX rotary
    for (int idx = l; idx < NN * 32; idx += 64) {
        int n = idx >> 5, i = idx & 31;
        float invf = expf(-(float)i * (9.2103403720f / 32.f));
        float cc = cosf((float)n * invf), ss = sinf((float)n * invf);
        float qlo = b2f(basep[n * 1536 + i]), qhi = b2f(basep[n * 1536 + i + 32]);
        sxq[n][i]      = f2b(qlo * cc - qhi * ss);
        sxq[n][i + 32] = f2b(qhi * cc + qlo * ss);
        float klo = b2f(basep[n * 1536 + 512 + i]), khi = b2f(basep[n * 1536 + 512 + i + 32]);
        sxk[n][i]      = f2b(klo * cc - khi * ss);
        sxk[n][i + 32] = f2b(khi * cc + klo * ss);
    }
    for (int idx = l; idx < NN * 64; idx += 64) {
        int n = idx >> 6, e = idx & 63;
        sVT[e][n] = basep[n * 1536 + 1024 + e];
    }
    __syncthreads();
    // sim = q@k^T * 0.125
    f4 acc = {};
    #pragma unroll
    for (int ks = 0; ks < 2; ++ks) {
        s8b aq = *(const s8b*)&sxq[i16][ks * 32 + g * 8];
        s8b bk = *(const s8b*)&sxk[i16][ks * 32 + g * 8];
        acc = __builtin_amdgcn_mfma_f32_16x16x32_bf16(aq, bk, acc, 0, 0, 0);
    }
    // softmax rows; col 15 masked
    #pragma unroll
    for (int j = 0; j < 4; ++j) {
        float v = (i16 == 15) ? -1e30f : acc[j] * 0.125f;
        float mx = v;
        mx = fmaxf(mx, __shfl_xor(mx, 1));
        mx = fmaxf(mx, __shfl_xor(mx, 2));
        mx = fmaxf(mx, __shfl_xor(mx, 4));
        mx = fmaxf(mx, __shfl_xor(mx, 8));
        float e = (i16 == 15) ? 0.f : expf(v - mx);
        float s = e;
        s += __shfl_xor(s, 1); s += __shfl_xor(s, 2);
        s += __shfl_xor(s, 4); s += __shfl_xor(s, 8);
        sA[g * 4 + j][i16] = f2b(e);
        if (i16 == 0) sdinv[g * 4 + j] = 1.f / s;
    }
    __syncthreads();
    // PV
    s8b aA = *(const s8b*)&sA[i16][g * 8];
    #pragma unroll
    for (int et = 0; et < 4; ++et) {
        s8b bV = *(const s8b*)&sVT[et * 16 + i16][g * 8];
        f4 z = {};
        f4 o = __builtin_amdgcn_mfma_f32_16x16x32_bf16(aA, bV, z, 0, 0, 0);
        #pragma unroll
        for (int j = 0; j < 4; ++j) {
            int n = g * 4 + j;
            if (n < NN)
                outp[((size_t)(b * NN + n)) * DIMM + h * 64 + et * 16 + i16] = f2b(o[j] * sdinv[n]);
        }
    }
}

// ---------------------------------------------------------------- final head
__global__ __launch_bounds__(256) void k_head(const float* __restrict__ logits,
                                              const float* __restrict__ Wl1,
                                              const float* __restrict__ bl1,
                                              const float* __restrict__ Wl2,
                                              const float* __restrict__ bl2,
                                              float* __restrict__ outp) {
    __shared__ float xa[NVOCAB];
    __shared__ float hh[64];
    int b = blockIdx.x, tid = threadIdx.x;
    for (int c = tid; c < NVOCAB; c += 256) {
        float s = 0.f;
        #pragma unroll
        for (int n = 0; n < NN; ++n) s += logits[((size_t)(b * NN + n)) * NVOCAB + c];
        xa[c] = s * (1.f / NN);
    }
    __syncthreads();
    if (tid < 64) {
        float s = bl1[tid];
        for (int kk = 0; kk < NVOCAB; ++kk) s += xa[kk] * Wl1[kk * 64 + tid];
        hh[tid] = fmaxf(s, 0.f);
    }
    __syncthreads();
    if (tid < 2) {
        float s = bl2[tid];
        #pragma unroll
        for (int j = 0; j < 64; ++j) s += hh[j] * Wl2[j * 2 + tid];
        outp[(size_t)b * 2 + tid] = s;
    }
}

// ---------------------------------------------------------------- host
extern "C" void kernel_launch(void* const* d_in, const int* in_sizes, int n_in,
                              void* d_out, int out_size, void* d_ws, size_t ws_size,
                              hipStream_t stream) {
    (void)in_sizes; (void)n_in; (void)out_size; (void)ws_size;
    const int*   x_mcc = (const int*)d_in[0];
    const float* emb   = (const float*)d_in[1];
    const float* ln1g  = (const float*)d_in[2];
    const float* ln1b  = (const float*)d_in[3];
    const float* Wq    = (const float*)d_in[4];
    const float* Wk    = (const float*)d_in[5];
    const float* Wv    = (const float*)d_in[6];
    const float* Wo    = (const float*)d_in[7];
    const float* bo    = (const float*)d_in[8];
    const float* proj  = (const float*)d_in[9];
    const float* ln2g  = (const float*)d_in[10];
    const float* ln2b  = (const float*)d_in[11];
    const float* W1    = (const float*)d_in[12];
    const float* b1    = (const float*)d_in[13];
    const float* W2    = (const float*)d_in[14];
    const float* b2    = (const float*)d_in[15];
    const float* lnfg  = (const float*)d_in[16];
    const float* lnfb  = (const float*)d_in[17];
    const float* Wout  = (const float*)d_in[18];
    const float* bout  = (const float*)d_in[19];
    const float* Wl1   = (const float*)d_in[20];
    const float* bl1   = (const float*)d_in[21];
    const float* Wl2   = (const float*)d_in[22];
    const float* bl2   = (const float*)d_in[23];
    float* outp = (float*)d_out;

    // ws layout (S = ROWS*512*4 = 62.9MB): x1(S) x2(S) xs(S/2,bf16) qkv(1.5S,bf16)
    //   ub(S,bf16 [30720][1024]) wbuf(~8.4MB). logits fp32 2S aliases qkv+ub.
    char* ws = (char*)d_ws;
    const size_t S = (size_t)ROWS * DIMM * 4;
    float*  x1   = (float*)(ws);
    float*  x2   = (float*)(ws + S);
    ushort* xs   = (ushort*)(ws + 2 * S);
    ushort* qkv  = (ushort*)(ws + 2 * S + S / 2);
    ushort* ub   = (ushort*)(ws + 4 * S);
    ushort* wb   = (ushort*)(ws + 5 * S);
    float*  logits = (float*)(ws + 2 * S + S / 2);
    ushort* qkvT = wb;                               // [1536][512]
    ushort* woT  = wb + 1536 * 512;                  // [512][512]
    ushort* w1T  = wb + 1536 * 512 + 512 * 512;      // [4096][512]
    ushort* w2T  = w1T + 4096 * 512;                 // [512][2048]
    ushort* projb = w2T + 512 * 2048;                // [12][256][64] bf16
    ushort* woutT = w1T;                             // [1024][512], reused at end

    k_embed<<<(ROWS * DIMM) / 256, 256, 0, stream>>>(x_mcc, emb, x1, x2);
    k_projcvt<<<(NLAYERS * MF * DHH) / 256, 256, 0, stream>>>(proj, projb, NLAYERS * MF * DHH);

    for (int l = 0; l < NLAYERS; ++l) {
        const size_t w512 = (size_t)l * 512 * 512;
        k_wt<<<dim3(16, 16), 256, 0, stream>>>(Wq + w512, qkvT,              512, 512);
        k_wt<<<dim3(16, 16), 256, 0, stream>>>(Wk + w512, qkvT + 512 * 512,  512, 512);
        k_wt<<<dim3(16, 16), 256, 0, stream>>>(Wv + w512, qkvT + 1024 * 512, 512, 512);
        k_wt<<<dim3(16, 16), 256, 0, stream>>>(Wo + w512, woT, 512, 512);
        k_wt<<<dim3(128, 16), 256, 0, stream>>>(W1 + (size_t)l * 512 * 4096, w1T, 512, 4096);
        k_wt<<<dim3(16, 64), 256, 0, stream>>>(W2 + (size_t)l * 2048 * 512, w2T, 2048, 512);

        k_ln<1, 0><<<BB, 256, 0, stream>>>(x2, nullptr, ln1g + l * DIMM, ln1b + l * DIMM, xs);
        k_mm<1, 0, 0><<<dim3(RT, 24), 256, 0, stream>>>(xs, qkvT, nullptr, nullptr, qkv, 512, 512, 512, 1536);
        k_attng<<<dim3(BB, GHH), 256, 0, stream>>>(qkv, projb + (size_t)l * MF * DHH, xs);
        k_attnl<<<dim3(BB, NH - GHH), 64, 0, stream>>>(qkv, xs);
        k_mm<0, 1, 1><<<dim3(RT, 8), 256, 0, stream>>>(xs, woT, bo + l * DIMM, x1, x1, 512, 512, 512, 512);
        k_ln<1, 0><<<BB, 256, 0, stream>>>(x1, nullptr, ln2g + l * DIMM, ln2b + l * DIMM, xs);
        // GLU chunk 0: hidden cols 0..1023 (a), 2048..3071 (g)
        k_glu<<<dim3(RT, 16), 256, 0, stream>>>(xs, w1T, w1T + (size_t)2048 * 512,
                                                b1 + (size_t)l * 4096, b1 + (size_t)l * 4096 + 2048, ub);
        k_mm<0, 1, 1><<<dim3(RT, 8), 256, 0, stream>>>(ub, w2T, b2 + l * DIMM, x2, x2, 1024, 2048, 1024, 512);
        // GLU chunk 1: hidden cols 1024..2047 (a), 3072..4095 (g)
        k_glu<<<dim3(RT, 16), 256, 0, stream>>>(xs, w1T + (size_t)1024 * 512, w1T + (size_t)3072 * 512,
                                                b1 + (size_t)l * 4096 + 1024, b1 + (size_t)l * 4096 + 3072, ub);
        k_mm<0, 0, 1><<<dim3(RT, 8), 256, 0, stream>>>(ub, w2T + 1024, nullptr, x2, x2, 1024, 2048, 1024, 512);
    }

    k_ln<0, 1><<<BB, 256, 0, stream>>>(x1, x2, lnfg, lnfb, xs);
    k_wt<<<dim3(32, 16), 256, 0, stream>>>(Wout, woutT, 512, 1024);
    k_mm<0, 1, 0><<<dim3(RT, 16), 256, 0, stream>>>(xs, woutT, bout, nullptr, logits, 512, 512, 512, 1024);
    k_head<<<BB, 256, 0, stream>>>(logits, Wl1, bl1, Wl2, bl2, outp);
}

// Round 8
// 7911.523 us; speedup vs baseline: 5.5146x; 1.0449x over previous
//
#include <hip/hip_runtime.h>
#include <math.h>

#define BB 2048
#define NN 15
#define DIMM 512
#define NH 8
#define GHH 4
#define DHH 64
#define MF 256
#define NLAYERS 12
#define NVOCAB 1024
#define ROWS (BB*NN)          // 30720
#define RT (ROWS/128)         // 240 row tiles

typedef __attribute__((ext_vector_type(8))) short s8b;
typedef __attribute__((ext_vector_type(4))) short s4b;
typedef __attribute__((ext_vector_type(4))) float f4;
typedef unsigned short ushort;
typedef unsigned int uint;

__device__ __forceinline__ ushort f2b(float f) {
    uint u = __builtin_bit_cast(uint, f);
    u = u + 0x7FFF + ((u >> 16) & 1);
    return (ushort)(u >> 16);
}
__device__ __forceinline__ float b2f(ushort b) {
    return __builtin_bit_cast(float, (uint)b << 16);
}
__device__ __forceinline__ void gll16(const ushort* g, ushort* l) {
    __builtin_amdgcn_global_load_lds(
        (const __attribute__((address_space(1))) uint*)g,
        (__attribute__((address_space(3))) uint*)l, 16, 0, 0);
}

// ---------------------------------------------------------------- embed
__global__ __launch_bounds__(256) void k_embed(const int* __restrict__ xm,
                                               const float* __restrict__ emb,
                                               float* __restrict__ x1,
                                               float* __restrict__ x2) {
    int idx = blockIdx.x * 256 + threadIdx.x;
    int row = idx >> 9;
    int d   = idx & 511;
    int n   = row % NN;
    int tok = xm[row];
    int j   = d & 255;
    float invf = expf(-(float)j * (9.2103403720f / 256.f));
    float arg  = (float)n * invf;
    float pe   = (d < 256) ? sinf(arg) : cosf(arg);
    float val  = emb[tok * DIMM + d] + pe;
    x1[idx] = val;
    x2[idx] = val;
}

// ---------------------------------------------------------------- layernorm (+optional add)(+pre_shift), bf16 out
template<int SHIFT, int ADD>
__global__ __launch_bounds__(256) void k_ln(const float* __restrict__ src,
                                            const float* __restrict__ src2,
                                            const float* __restrict__ gg,
                                            const float* __restrict__ bb,
                                            ushort* __restrict__ dst) {
    __shared__ float buf[NN][DIMM];
    int b    = blockIdx.x;
    int tid  = threadIdx.x;
    int wid  = tid >> 6;
    int lane = tid & 63;

    for (int n = wid; n < NN; n += 4) {
        size_t base = ((size_t)(b * NN + n)) * DIMM;
        float4 v0 = *(const float4*)(src + base + lane * 8);
        float4 v1 = *(const float4*)(src + base + lane * 8 + 4);
        if (ADD) {
            float4 w0 = *(const float4*)(src2 + base + lane * 8);
            float4 w1 = *(const float4*)(src2 + base + lane * 8 + 4);
            v0.x += w0.x; v0.y += w0.y; v0.z += w0.z; v0.w += w0.w;
            v1.x += w1.x; v1.y += w1.y; v1.z += w1.z; v1.w += w1.w;
        }
        float s = v0.x + v0.y + v0.z + v0.w + v1.x + v1.y + v1.z + v1.w;
        #pragma unroll
        for (int m = 1; m < 64; m <<= 1) s += __shfl_xor(s, m);
        float mu = s * (1.f / DIMM);
        float a0 = v0.x - mu, a1 = v0.y - mu, a2 = v0.z - mu, a3 = v0.w - mu;
        float a4 = v1.x - mu, a5 = v1.y - mu, a6 = v1.z - mu, a7 = v1.w - mu;
        float s2 = a0*a0 + a1*a1 + a2*a2 + a3*a3 + a4*a4 + a5*a5 + a6*a6 + a7*a7;
        #pragma unroll
        for (int m = 1; m < 64; m <<= 1) s2 += __shfl_xor(s2, m);
        float rstd = 1.f / sqrtf(s2 * (1.f / DIMM) + 1e-5f);
        float o[8] = {a0, a1, a2, a3, a4, a5, a6, a7};
        int d0 = lane * 8;
        #pragma unroll
        for (int i = 0; i < 8; ++i) {
            float val = o[i] * rstd * gg[d0 + i] + bb[d0 + i];
            if (SHIFT) buf[n][d0 + i] = val;
            else       dst[base + d0 + i] = f2b(val);
        }
    }
    if (SHIFT) {
        __syncthreads();
        for (int idx = tid; idx < NN * DIMM; idx += 256) {
            int n = idx >> 9, d = idx & 511;
            float val;
            if (d < 170)      val = (n < NN - 1) ? buf[n + 1][d] : 0.f;
            else if (d < 340) val = buf[n][d];
            else if (d < 510) val = (n > 0) ? buf[n - 1][d] : 0.f;
            else              val = buf[n][d];
            dst[((size_t)(b * NN + n)) * DIMM + d] = f2b(val);
        }
    }
}

// ---------------------------------------------------------------- weight transpose fp32[K][N] -> bf16[N][K]
__global__ __launch_bounds__(256) void k_wt(const float* __restrict__ src,
                                            ushort* __restrict__ dst, int K, int N) {
    __shared__ float t[32][33];
    int n0 = blockIdx.x * 32, k0 = blockIdx.y * 32;
    int tx = threadIdx.x & 31, ty = threadIdx.x >> 5;
    #pragma unroll
    for (int i = 0; i < 32; i += 8)
        t[ty + i][tx] = src[(size_t)(k0 + ty + i) * N + n0 + tx];
    __syncthreads();
    #pragma unroll
    for (int i = 0; i < 32; i += 8)
        dst[(size_t)(n0 + ty + i) * K + k0 + tx] = f2b(t[tx][ty + i]);
}

// ---------------------------------------------------------------- W1 paired transpose: fp32[512][4096] -> bf16[4096][512]
// paired rows: row 2p = W1 col p (a-part), row 2p+1 = W1 col 2048+p (g-part)
__global__ __launch_bounds__(256) void k_wtp(const float* __restrict__ src,
                                             ushort* __restrict__ dst) {
    __shared__ float t[32][33];
    int c0 = blockIdx.x * 32, k0 = blockIdx.y * 32;
    int tx = threadIdx.x & 31, ty = threadIdx.x >> 5;
    #pragma unroll
    for (int i = 0; i < 32; i += 8)
        t[ty + i][tx] = src[(size_t)(k0 + ty + i) * 4096 + c0 + tx];
    __syncthreads();
    #pragma unroll
    for (int i = 0; i < 32; i += 8) {
        int c = c0 + ty + i;
        int rr = (c < 2048) ? 2 * c : 2 * (c - 2048) + 1;
        dst[(size_t)rr * 512 + k0 + tx] = f2b(t[tx][ty + i]);
    }
}

// ---------------------------------------------------------------- proj fp32 -> bf16 (all layers)
__global__ __launch_bounds__(256) void k_projcvt(const float* __restrict__ src,
                                                 ushort* __restrict__ dst, int n) {
    int i = blockIdx.x * 256 + threadIdx.x;
    if (i < n) dst[i] = f2b(src[i]);
}

// ---------------------------------------------------------------- bf16 MFMA GEMM: out = A[M,K](bf16) @ Bt[N,K](bf16)^T
// m97 structure: 128x128 tile, BK=32, 4 waves (2x2), 4x4 frags (64 AGPR),
// 2-phase double-buffer: STAGE(t+1) || compute(t); one barrier per K-step.
template<int OUTB, int BIAS, int RES>
__global__ __launch_bounds__(256) void k_mm(const ushort* __restrict__ A,
                                            const ushort* __restrict__ Bt,
                                            const float* __restrict__ bias,
                                            const float* __restrict__ res,
                                            void* __restrict__ outv,
                                            int lda, int ldb, int K, int ldo) {
    __shared__ ushort smA[2][128 * 32];
    __shared__ ushort smB[2][128 * 32];
    int tid = threadIdx.x, wid = tid >> 6, lane = tid & 63;
    int i16 = lane & 15, g = lane >> 4;
    int row0 = blockIdx.x * 128, col0 = blockIdx.y * 128;
    int rw = (wid >> 1) * 64, cw = (wid & 1) * 64;
    int trow = tid >> 2, tkk = (tid & 3) * 8;
    f4 acc[4][4] = {};
    const int NT = K >> 5;

    auto STAGE = [&](int c, int k0) {
        gll16(A  + (size_t)(row0 + trow) * lda + k0 + tkk,      &smA[c][tid * 8]);
        gll16(A  + (size_t)(row0 + 64 + trow) * lda + k0 + tkk, &smA[c][2048 + tid * 8]);
        gll16(Bt + (size_t)(col0 + trow) * ldb + k0 + tkk,      &smB[c][tid * 8]);
        gll16(Bt + (size_t)(col0 + 64 + trow) * ldb + k0 + tkk, &smB[c][2048 + tid * 8]);
    };

    STAGE(0, 0);
    __syncthreads();
    for (int t = 0; t < NT; ++t) {
        int cur = t & 1;
        if (t + 1 < NT) STAGE(cur ^ 1, (t + 1) * 32);
        s8b af[4], bf[4];
        #pragma unroll
        for (int m = 0; m < 4; ++m)
            af[m] = *(const s8b*)&smA[cur][(rw + m * 16 + i16) * 32 + g * 8];
        #pragma unroll
        for (int n = 0; n < 4; ++n)
            bf[n] = *(const s8b*)&smB[cur][(cw + n * 16 + i16) * 32 + g * 8];
        #pragma unroll
        for (int m = 0; m < 4; ++m)
            #pragma unroll
            for (int n = 0; n < 4; ++n)
                acc[m][n] = __builtin_amdgcn_mfma_f32_16x16x32_bf16(af[m], bf[n], acc[m][n], 0, 0, 0);
        __syncthreads();
    }
    #pragma unroll
    for (int m = 0; m < 4; ++m) {
        #pragma unroll
        for (int n = 0; n < 4; ++n) {
            int c = col0 + cw + n * 16 + i16;
            #pragma unroll
            for (int j = 0; j < 4; ++j) {
                int r = row0 + rw + m * 16 + g * 4 + j;
                float v = acc[m][n][j];
                if (BIAS) v += bias[c];
                if (RES)  v += res[(size_t)r * ldo + c];
                if (OUTB) ((ushort*)outv)[(size_t)r * ldo + c] = f2b(v);
                else      ((float*)outv)[(size_t)r * ldo + c] = v;
            }
        }
    }
}

// ---------------------------------------------------------------- GLU FF1 as paired GEMM: Bp rows 2p=Wa_p, 2p+1=Wg_p.
// Same structure as k_mm; epilogue pairs adjacent lanes (shfl_xor 1) for gelu(a)*g.
__global__ __launch_bounds__(256) void k_glup(const ushort* __restrict__ A,
                                              const ushort* __restrict__ Bp,
                                              const float* __restrict__ b1l,
                                              ushort* __restrict__ outp) {
    __shared__ ushort smA[2][128 * 32];
    __shared__ ushort smB[2][128 * 32];
    int tid = threadIdx.x, wid = tid >> 6, lane = tid & 63;
    int i16 = lane & 15, g = lane >> 4;
    int row0 = blockIdx.x * 128, col0 = blockIdx.y * 128;
    int rw = (wid >> 1) * 64, cw = (wid & 1) * 64;
    int trow = tid >> 2, tkk = (tid & 3) * 8;
    f4 acc[4][4] = {};

    auto STAGE = [&](int c, int k0) {
        gll16(A  + (size_t)(row0 + trow) * 512 + k0 + tkk,      &smA[c][tid * 8]);
        gll16(A  + (size_t)(row0 + 64 + trow) * 512 + k0 + tkk, &smA[c][2048 + tid * 8]);
        gll16(Bp + (size_t)(col0 + trow) * 512 + k0 + tkk,      &smB[c][tid * 8]);
        gll16(Bp + (size_t)(col0 + 64 + trow) * 512 + k0 + tkk, &smB[c][2048 + tid * 8]);
    };

    STAGE(0, 0);
    __syncthreads();
    for (int t = 0; t < 16; ++t) {
        int cur = t & 1;
        if (t + 1 < 16) STAGE(cur ^ 1, (t + 1) * 32);
        s8b af[4], bf[4];
        #pragma unroll
        for (int m = 0; m < 4; ++m)
            af[m] = *(const s8b*)&smA[cur][(rw + m * 16 + i16) * 32 + g * 8];
        #pragma unroll
        for (int n = 0; n < 4; ++n)
            bf[n] = *(const s8b*)&smB[cur][(cw + n * 16 + i16) * 32 + g * 8];
        #pragma unroll
        for (int m = 0; m < 4; ++m)
            #pragma unroll
            for (int n = 0; n < 4; ++n)
                acc[m][n] = __builtin_amdgcn_mfma_f32_16x16x32_bf16(af[m], bf[n], acc[m][n], 0, 0, 0);
        __syncthreads();
    }
    // epilogue: col c in paired space; even c -> a, odd c -> g of pair p=c>>1
    #pragma unroll
    for (int m = 0; m < 4; ++m) {
        #pragma unroll
        for (int n = 0; n < 4; ++n) {
            int c = col0 + cw + n * 16 + i16;
            int p = c >> 1;
            float bv = b1l[(c & 1) * 2048 + p];
            #pragma unroll
            for (int j = 0; j < 4; ++j) {
                int r = row0 + rw + m * 16 + g * 4 + j;
                float v = acc[m][n][j] + bv;
                float w = __shfl_xor(v, 1);          // partner lane: a<->g
                if (!(c & 1)) {
                    float ge = 0.5f * v * (1.f + erff(v * 0.70710678118f));
                    outp[(size_t)r * 2048 + p] = f2b(ge * w);
                }
            }
        }
    }
}

// ---------------------------------------------------------------- global-head attention (performer) via MFMA
__global__ __launch_bounds__(256) void k_attng(const ushort* __restrict__ qkv,
                                               const ushort* __restrict__ projb,
                                               ushort* __restrict__ outp) {
    __shared__ ushort sxq[16][72];      // rotated q bf16, row15 zero, padded stride
    __shared__ ushort sxk[16][72];
    __shared__ ushort sVT[64][40];      // V^T (e-major), cols>=15 zero
    __shared__ ushort sqp[16][264];     // qp features bf16
    __shared__ ushort skp[16][264];
    __shared__ ushort sA[16][40];       // scores bf16, cols>=15 zero
    __shared__ float sdq[16], sdk[16], sdinv[16];
    __shared__ float sPq[4][16];
    __shared__ float sPk[4];
    int b = blockIdx.x, h = blockIdx.y;
    int tid = threadIdx.x, w = tid >> 6, l = tid & 63;
    int i16 = l & 15, g = l >> 4;
    const ushort* basep = qkv + (size_t)b * NN * 1536 + h * 64;

    {   // zero pads
        uint* z1 = (uint*)&sVT[0][0];
        for (int i = tid; i < 1280; i += 256) z1[i] = 0;
        uint* z2 = (uint*)&sA[0][0];
        for (int i = tid; i < 320; i += 256) z2[i] = 0;
        if (tid < 64) { sxq[15][tid] = 0; sxk[15][tid] = 0; }
    }
    __syncthreads();
    // load + GPT-J rotary; V transposed
    for (int idx = tid; idx < NN * 32; idx += 256) {
        int n = idx >> 5, i = idx & 31;
        float invf = expf(-(float)i * (9.2103403720f / 32.f));
        float cc = cosf((float)n * invf), ss = sinf((float)n * invf);
        float q0 = b2f(basep[n * 1536 + 2 * i]), q1 = b2f(basep[n * 1536 + 2 * i + 1]);
        sxq[n][2 * i]     = f2b(q0 * cc - q1 * ss);
        sxq[n][2 * i + 1] = f2b(q1 * cc + q0 * ss);
        float k0 = b2f(basep[n * 1536 + 512 + 2 * i]), k1 = b2f(basep[n * 1536 + 512 + 2 * i + 1]);
        sxk[n][2 * i]     = f2b(k0 * cc - k1 * ss);
        sxk[n][2 * i + 1] = f2b(k1 * cc + k0 * ss);
    }
    for (int idx = tid; idx < NN * 64; idx += 256) {
        int n = idx >> 6, e = idx & 63;
        sVT[e][n] = basep[n * 1536 + 1024 + e];
    }
    __syncthreads();
    // diag (wave 0): 0.5*dn^2*||x||^2 per row
    if (w == 0) {
        int n = l >> 2, c = l & 3;
        float sa = 0.f, sb = 0.f;
        #pragma unroll
        for (int s = 0; s < 2; ++s) {
            s8b vq = *(const s8b*)&sxq[n][c * 16 + s * 8];
            s8b vk = *(const s8b*)&sxk[n][c * 16 + s * 8];
            #pragma unroll
            for (int j = 0; j < 8; ++j) {
                float x = b2f((ushort)vq[j]); sa += x * x;
                float y = b2f((ushort)vk[j]); sb += y * y;
            }
        }
        sa += __shfl_xor(sa, 1); sa += __shfl_xor(sa, 2);
        sb += __shfl_xor(sb, 1); sb += __shfl_xor(sb, 2);
        if (c == 0) { sdq[n] = 0.0625f * sa; sdk[n] = 0.0625f * sb; }
    }
    // dash MFMA: D[m][n] = sum_d proj[m][d]*x[n][d] (unscaled)
    s8b bq[2], bk[2];
    bq[0] = *(const s8b*)&sxq[i16][g * 8];
    bq[1] = *(const s8b*)&sxq[i16][32 + g * 8];
    bk[0] = *(const s8b*)&sxk[i16][g * 8];
    bk[1] = *(const s8b*)&sxk[i16][32 + g * 8];
    f4 accq[4] = {}, acck[4] = {};
    const ushort* pb = projb + (size_t)(w * 64 + i16) * 64 + g * 8;
    #pragma unroll
    for (int mi = 0; mi < 4; ++mi) {
        #pragma unroll
        for (int ks = 0; ks < 2; ++ks) {
            s8b a = *(const s8b*)(pb + mi * 16 * 64 + ks * 32);
            accq[mi] = __builtin_amdgcn_mfma_f32_16x16x32_bf16(a, bq[ks], accq[mi], 0, 0, 0);
            acck[mi] = __builtin_amdgcn_mfma_f32_16x16x32_bf16(a, bk[ks], acck[mi], 0, 0, 0);
        }
    }
    // maxes: per-row (q), global over n<15,m (k)
    float mq = -1e30f, mkv = -1e30f;
    #pragma unroll
    for (int mi = 0; mi < 4; ++mi)
        #pragma unroll
        for (int j = 0; j < 4; ++j) {
            mq  = fmaxf(mq, accq[mi][j]);
            mkv = fmaxf(mkv, acck[mi][j]);
        }
    if (i16 == 15) mkv = -1e30f;
    mq = fmaxf(mq, __shfl_xor(mq, 16));
    mq = fmaxf(mq, __shfl_xor(mq, 32));
    #pragma unroll
    for (int m = 1; m < 64; m <<= 1) mkv = fmaxf(mkv, __shfl_xor(mkv, m));
    if (l < 16) sPq[w][l] = mq;
    if (l == 0) sPk[w] = mkv;
    __syncthreads();
    float mxq = fmaxf(fmaxf(sPq[0][i16], sPq[1][i16]), fmaxf(sPq[2][i16], sPq[3][i16]));
    float mxk = fmaxf(fmaxf(sPk[0], sPk[1]), fmaxf(sPk[2], sPk[3]));
    // qp/kp features -> LDS bf16
    const float dn = 0.35355339059f;   // 64^-0.25
    float dgq = sdq[i16], dgk = sdk[i16];
    #pragma unroll
    for (int mi = 0; mi < 4; ++mi) {
        s4b pq, pk;
        #pragma unroll
        for (int j = 0; j < 4; ++j) {
            float vq = 0.0625f * (expf(dn * (accq[mi][j] - mxq) - dgq) + 1e-4f);
            float vk = 0.0625f * (expf(dn * (acck[mi][j] - mxk) - dgk) + 1e-4f);
            pq[j] = (short)f2b(vq);
            pk[j] = (short)f2b(vk);
        }
        int m0 = (w * 4 + mi) * 16 + g * 4;
        *(s4b*)&sqp[i16][m0] = pq;
        *(s4b*)&skp[i16][m0] = pk;
    }
    __syncthreads();
    // scores A = qp @ kp^T (wave 0), rowsum -> d_inv; col 15 masked
    if (w == 0) {
        f4 accA = {};
        #pragma unroll
        for (int ks = 0; ks < 8; ++ks) {
            s8b aq = *(const s8b*)&sqp[i16][ks * 32 + g * 8];
            s8b ak = *(const s8b*)&skp[i16][ks * 32 + g * 8];
            accA = __builtin_amdgcn_mfma_f32_16x16x32_bf16(aq, ak, accA, 0, 0, 0);
        }
        #pragma unroll
        for (int j = 0; j < 4; ++j) {
            float v = (i16 == 15) ? 0.f : accA[j];
            float s = v;
            s += __shfl_xor(s, 1); s += __shfl_xor(s, 2);
            s += __shfl_xor(s, 4); s += __shfl_xor(s, 8);
            sA[g * 4 + j][i16] = f2b(v);
            if (i16 == 0) sdinv[g * 4 + j] = 1.f / s;
        }
    }
    __syncthreads();
    // PV: wave w does e-tile w
    {
        s8b aA = *(const s8b*)&sA[i16][g * 8];
        s8b bV = *(const s8b*)&sVT[w * 16 + i16][g * 8];
        f4 z = {};
        f4 o = __builtin_amdgcn_mfma_f32_16x16x32_bf16(aA, bV, z, 0, 0, 0);
        #pragma unroll
        for (int j = 0; j < 4; ++j) {
            int n = g * 4 + j;
            if (n < NN)
                outp[((size_t)(b * NN + n)) * DIMM + h * 64 + w * 16 + i16] = f2b(o[j] * sdinv[n]);
        }
    }
}

// ---------------------------------------------------------------- local-head attention (softmax) via MFMA, 1 wave
__global__ __launch_bounds__(64) void k_attnl(const ushort* __restrict__ qkv,
                                              ushort* __restrict__ outp) {
    __shared__ ushort sxq[16][72];
    __shared__ ushort sxk[16][72];
    __shared__ ushort sVT[64][40];
    __shared__ ushort sA[16][40];
    __shared__ float sdinv[16];
    int b = blockIdx.x, h = blockIdx.y + GHH;
    int l = threadIdx.x;
    int i16 = l & 15, g = l >> 4;
    const ushort* basep = qkv + (size_t)b * NN * 1536 + h * 64;

    {
        uint* z1 = (uint*)&sVT[0][0];
        for (int i = l; i < 1280; i += 64) z1[i] = 0;
        uint* z2 = (uint*)&sA[0][0];
        for (int i = l; i < 320; i += 64) z2[i] = 0;
        sxq[15][l] = 0; sxk[15][l] = 0;
    }
    __syncthreads();
    // NeoX rotary
    for (int idx = l; idx < NN * 32; idx += 64) {
        int n = idx >> 5, i = idx & 31;
        float invf = expf(-(float)i * (9.2103403720f / 32.f));
        float cc = cosf((float)n * invf), ss = sinf((float)n * invf);
        float qlo = b2f(basep[n * 1536 + i]), qhi = b2f(basep[n * 1536 + i + 32]);
        sxq[n][i]      = f2b(qlo * cc - qhi * ss);
        sxq[n][i + 32] = f2b(qhi * cc + qlo * ss);
        float klo = b2f(basep[n * 1536 + 512 + i]), khi = b2f(basep[n * 1536 + 512 + i + 32]);
        sxk[n][i]      = f2b(klo * cc - khi * ss);
        sxk[n][i + 32] = f2b(khi * cc + klo * ss);
    }
    for (int idx = l; idx < NN * 64; idx += 64) {
        int n = idx >> 6, e = idx & 63;
        sVT[e][n] = basep[n * 1536 + 1024 + e];
    }
    __syncthreads();
    // sim = q@k^T * 0.125
    f4 acc = {};
    #pragma unroll
    for (int ks = 0; ks < 2; ++ks) {
        s8b aq = *(const s8b*)&sxq[i16][ks * 32 + g * 8];
        s8b bk = *(const s8b*)&sxk[i16][ks * 32 + g * 8];
        acc = __builtin_amdgcn_mfma_f32_16x16x32_bf16(aq, bk, acc, 0, 0, 0);
    }
    // softmax rows; col 15 masked
    #pragma unroll
    for (int j = 0; j < 4; ++j) {
        float v = (i16 == 15) ? -1e30f : acc[j] * 0.125f;
        float mx = v;
        mx = fmaxf(mx, __shfl_xor(mx, 1));
        mx = fmaxf(mx, __shfl_xor(mx, 2));
        mx = fmaxf(mx, __shfl_xor(mx, 4));
        mx = fmaxf(mx, __shfl_xor(mx, 8));
        float e = (i16 == 15) ? 0.f : expf(v - mx);
        float s = e;
        s += __shfl_xor(s, 1); s += __shfl_xor(s, 2);
        s += __shfl_xor(s, 4); s += __shfl_xor(s, 8);
        sA[g * 4 + j][i16] = f2b(e);
        if (i16 == 0) sdinv[g * 4 + j] = 1.f / s;
    }
    __syncthreads();
    // PV
    s8b aA = *(const s8b*)&sA[i16][g * 8];
    #pragma unroll
    for (int et = 0; et < 4; ++et) {
        s8b bV = *(const s8b*)&sVT[et * 16 + i16][g * 8];
        f4 z = {};
        f4 o = __builtin_amdgcn_mfma_f32_16x16x32_bf16(aA, bV, z, 0, 0, 0);
        #pragma unroll
        for (int j = 0; j < 4; ++j) {
            int n = g * 4 + j;
            if (n < NN)
                outp[((size_t)(b * NN + n)) * DIMM + h * 64 + et * 16 + i16] = f2b(o[j] * sdinv[n]);
        }
    }
}

// ---------------------------------------------------------------- final head
__global__ __launch_bounds__(256) void k_head(const float* __restrict__ logits,
                                              const float* __restrict__ Wl1,
                                              const float* __restrict__ bl1,
                                              const float* __restrict__ Wl2,
                                              const float* __restrict__ bl2,
                                              float* __restrict__ outp) {
    __shared__ float xa[NVOCAB];
    __shared__ float hh[64];
    int b = blockIdx.x, tid = threadIdx.x;
    for (int c = tid; c < NVOCAB; c += 256) {
        float s = 0.f;
        #pragma unroll
        for (int n = 0; n < NN; ++n) s += logits[((size_t)(b * NN + n)) * NVOCAB + c];
        xa[c] = s * (1.f / NN);
    }
    __syncthreads();
    if (tid < 64) {
        float s = bl1[tid];
        for (int kk = 0; kk < NVOCAB; ++kk) s += xa[kk] * Wl1[kk * 64 + tid];
        hh[tid] = fmaxf(s, 0.f);
    }
    __syncthreads();
    if (tid < 2) {
        float s = bl2[tid];
        #pragma unroll
        for (int j = 0; j < 64; ++j) s += hh[j] * Wl2[j * 2 + tid];
        outp[(size_t)b * 2 + tid] = s;
    }
}

// ---------------------------------------------------------------- host
extern "C" void kernel_launch(void* const* d_in, const int* in_sizes, int n_in,
                              void* d_out, int out_size, void* d_ws, size_t ws_size,
                              hipStream_t stream) {
    (void)in_sizes; (void)n_in; (void)out_size; (void)ws_size;
    const int*   x_mcc = (const int*)d_in[0];
    const float* emb   = (const float*)d_in[1];
    const float* ln1g  = (const float*)d_in[2];
    const float* ln1b  = (const float*)d_in[3];
    const float* Wq    = (const float*)d_in[4];
    const float* Wk    = (const float*)d_in[5];
    const float* Wv    = (const float*)d_in[6];
    const float* Wo    = (const float*)d_in[7];
    const float* bo    = (const float*)d_in[8];
    const float* proj  = (const float*)d_in[9];
    const float* ln2g  = (const float*)d_in[10];
    const float* ln2b  = (const float*)d_in[11];
    const float* W1    = (const float*)d_in[12];
    const float* b1    = (const float*)d_in[13];
    const float* W2    = (const float*)d_in[14];
    const float* b2    = (const float*)d_in[15];
    const float* lnfg  = (const float*)d_in[16];
    const float* lnfb  = (const float*)d_in[17];
    const float* Wout  = (const float*)d_in[18];
    const float* bout  = (const float*)d_in[19];
    const float* Wl1   = (const float*)d_in[20];
    const float* bl1   = (const float*)d_in[21];
    const float* Wl2   = (const float*)d_in[22];
    const float* bl2   = (const float*)d_in[23];
    float* outp = (float*)d_out;

    // ws layout (S = ROWS*512*4 = 62.9MB):
    //   x1(S) x2(S) xs(S/2,bf16) | region 2.5S..4.5S: qkv(1.5S,bf16) then
    //   ub([30720][2048] bf16 = 2S) then logits(fp32 2S) | wb at 5S (~8.4MB).
    char* ws = (char*)d_ws;
    const size_t S = (size_t)ROWS * DIMM * 4;
    float*  x1   = (float*)(ws);
    float*  x2   = (float*)(ws + S);
    ushort* xs   = (ushort*)(ws + 2 * S);
    ushort* qkv  = (ushort*)(ws + 2 * S + S / 2);
    ushort* ub   = (ushort*)(ws + 2 * S + S / 2);   // [30720][2048], qkv dead by then
    float*  logits = (float*)(ws + 2 * S + S / 2);  // 2S, ub dead by then
    ushort* wb   = (ushort*)(ws + 5 * S);
    ushort* qkvT = wb;                               // [1536][512]
    ushort* woT  = wb + 1536 * 512;                  // [512][512]
    ushort* w1p  = wb + 1536 * 512 + 512 * 512;      // [4096][512] paired
    ushort* w2T  = w1p + 4096 * 512;                 // [512][2048]
    ushort* projb = w2T + 512 * 2048;                // [12][256][64] bf16
    ushort* woutT = w1p;                             // [1024][512], reused at end

    k_embed<<<(ROWS * DIMM) / 256, 256, 0, stream>>>(x_mcc, emb, x1, x2);
    k_projcvt<<<(NLAYERS * MF * DHH) / 256, 256, 0, stream>>>(proj, projb, NLAYERS * MF * DHH);

    for (int l = 0; l < NLAYERS; ++l) {
        const size_t w512 = (size_t)l * 512 * 512;
        k_wt<<<dim3(16, 16), 256, 0, stream>>>(Wq + w512, qkvT,              512, 512);
        k_wt<<<dim3(16, 16), 256, 0, stream>>>(Wk + w512, qkvT + 512 * 512,  512, 512);
        k_wt<<<dim3(16, 16), 256, 0, stream>>>(Wv + w512, qkvT + 1024 * 512, 512, 512);
        k_wt<<<dim3(16, 16), 256, 0, stream>>>(Wo + w512, woT, 512, 512);
        k_wtp<<<dim3(128, 16), 256, 0, stream>>>(W1 + (size_t)l * 512 * 4096, w1p);
        k_wt<<<dim3(16, 64), 256, 0, stream>>>(W2 + (size_t)l * 2048 * 512, w2T, 2048, 512);

        k_ln<1, 0><<<BB, 256, 0, stream>>>(x2, nullptr, ln1g + l * DIMM, ln1b + l * DIMM, xs);
        k_mm<1, 0, 0><<<dim3(RT, 12), 256, 0, stream>>>(xs, qkvT, nullptr, nullptr, qkv, 512, 512, 512, 1536);
        k_attng<<<dim3(BB, GHH), 256, 0, stream>>>(qkv, projb + (size_t)l * MF * DHH, xs);
        k_attnl<<<dim3(BB, NH - GHH), 64, 0, stream>>>(qkv, xs);
        k_mm<0, 1, 1><<<dim3(RT, 4), 256, 0, stream>>>(xs, woT, bo + l * DIMM, x1, x1, 512, 512, 512, 512);
        k_ln<1, 0><<<BB, 256, 0, stream>>>(x1, nullptr, ln2g + l * DIMM, ln2b + l * DIMM, xs);
        // GLU FF1: paired GEMM over N=4096 -> ub [30720][2048]
        k_glup<<<dim3(RT, 32), 256, 0, stream>>>(xs, w1p, b1 + (size_t)l * 4096, ub);
        // FF2: single K=2048 GEMM with residual
        k_mm<0, 1, 1><<<dim3(RT, 4), 256, 0, stream>>>(ub, w2T, b2 + l * DIMM, x2, x2, 2048, 2048, 2048, 512);
    }

    k_ln<0, 1><<<BB, 256, 0, stream>>>(x1, x2, lnfg, lnfb, xs);
    k_wt<<<dim3(32, 16), 256, 0, stream>>>(Wout, woutT, 512, 1024);
    k_mm<0, 1, 0><<<dim3(RT, 8), 256, 0, stream>>>(xs, woutT, bout, nullptr, logits, 512, 512, 512, 1024);
    k_head<<<BB, 256, 0, stream>>>(logits, Wl1, bl1, Wl2, bl2, outp);
}